// Round 13
// baseline (179.521 us; speedup 1.0000x reference)
//
#include <hip/hip_runtime.h>
#include <hip/hip_fp16.h>
#include <math.h>

#define LEAKY 0.2f
#define XPAD 136   // 128 + 8 halves row pad
#define MAXB 512   // max dst-buckets (128 nodes each; N<=65536)

typedef _Float16 f16x8 __attribute__((ext_vector_type(8)));
typedef float f32x4 __attribute__((ext_vector_type(4)));

__device__ inline int h2i(__half2 h) { union { __half2 h; int i; } u; u.h = h; return u.i; }
__device__ inline __half2 i2h(int i) { union { __half2 h; int i; } u; u.i = i; return u.h; }

// ====== CSR build: bucketed partition ======
__global__ __launch_bounds__(256) void k_bhist(const int* __restrict__ ei,
                                               int* __restrict__ gbcnt, int E, int PB)
{
  __shared__ int lh[MAXB];
  int t = threadIdx.x;
  for (int i = t; i < PB; i += 256) lh[i] = 0;
  __syncthreads();
  int base = blockIdx.x * 2048;
#pragma unroll
  for (int k = 0; k < 8; ++k) {
    int idx = base + t + k * 256;
    if (idx < E) atomicAdd(&lh[ei[E + idx] >> 7], 1);
  }
  __syncthreads();
  for (int i = t; i < PB; i += 256) if (lh[i]) atomicAdd(&gbcnt[i], lh[i]);
}

__global__ __launch_bounds__(512) void k_bscan(const int* __restrict__ gbcnt,
                                               int* __restrict__ pbase,
                                               int* __restrict__ gcur, int PB)
{
  __shared__ int ls[512];
  int t = threadIdx.x;
  int v = (t < PB) ? gbcnt[t] : 0;
  ls[t] = v;
  __syncthreads();
  for (int off = 1; off < 512; off <<= 1) {
    int u = (t >= off) ? ls[t - off] : 0;
    __syncthreads();
    ls[t] += u;
    __syncthreads();
  }
  int excl = ls[t] - v;
  if (t <= PB) pbase[t] = excl;
  if (t < PB) gcur[t] = excl;
}

// partition: single ei read (regs), per-block LDS counts -> bulk reserve -> runs
__global__ __launch_bounds__(256) void k_part(const int* __restrict__ ei,
                                              int* __restrict__ gcur,
                                              int2* __restrict__ pairs, int E, int PB)
{
  __shared__ int lcnt[MAXB], lbase[MAXB];
  int t = threadIdx.x;
  for (int i = t; i < PB; i += 256) lcnt[i] = 0;
  __syncthreads();
  int base = blockIdx.x * 4096;
  int lsrc[16], ldst[16], lp[16];
#pragma unroll
  for (int k = 0; k < 16; ++k) {
    int idx = base + t + k * 256;
    lp[k] = -1;
    if (idx < E) {
      int s = ei[idx], d = ei[E + idx];
      lsrc[k] = s; ldst[k] = d;
      int b = d >> 7;
      int p = atomicAdd(&lcnt[b], 1);
      lp[k] = (p << 10) | b;
    }
  }
  __syncthreads();
  for (int b = t; b < PB; b += 256) lbase[b] = atomicAdd(&gcur[b], lcnt[b]);
  __syncthreads();
#pragma unroll
  for (int k = 0; k < 16; ++k) {
    if (lp[k] >= 0) {
      int b = lp[k] & 1023, p = lp[k] >> 10;
      pairs[lbase[b] + p] = make_int2(lsrc[k], ldst[k]);
    }
  }
}

// per-bucket: local deg (+1 self) -> local scan = rowptr -> LDS-cursor scatter
__global__ __launch_bounds__(256) void k_fine(const int2* __restrict__ pairs,
                                              const int* __restrict__ pbase,
                                              int* __restrict__ rowptr,
                                              int* __restrict__ colx, int N)
{
  __shared__ int ldeg[128], lcur[128];
  int b = blockIdx.x, t = threadIdx.x;
  int nbase = b << 7;
  int nbn = N - nbase; if (nbn > 128) nbn = 128;
  if (t < 128) ldeg[t] = (t < nbn) ? 1 : 0;
  __syncthreads();
  int e0 = pbase[b], e1 = pbase[b + 1];
  for (int e = e0 + t; e < e1; e += 256) atomicAdd(&ldeg[pairs[e].y - nbase], 1);
  __syncthreads();
  int myv = (t < 128) ? ldeg[t] : 0;
  for (int off = 1; off < 128; off <<= 1) {
    int u = (t < 128 && t >= off) ? ldeg[t - off] : 0;
    __syncthreads();
    if (t < 128) ldeg[t] += u;
    __syncthreads();
  }
  int colx0 = e0 + nbase;
  if (t < 128) {
    int excl = ldeg[t] - myv;
    lcur[t] = colx0 + excl;
    int idx = nbase + t;
    if (idx <= N) rowptr[idx] = colx0 + excl;
  }
  __syncthreads();
  for (int e = e0 + t; e < e1; e += 256) {
    int2 p = pairs[e];
    int pos = atomicAdd(&lcur[p.y - nbase], 1);
    colx[pos] = p.x;
  }
  if (t < nbn) {
    int pos = atomicAdd(&lcur[t], 1);
    colx[pos] = nbase + t;
  }
}

// ====== GEMM1 (MFMA): h1 = x @ W1, fp16 out, fused att dots ======
__global__ __launch_bounds__(256) void k_gemm1(
    const float* __restrict__ x, const float* __restrict__ W,
    const float* __restrict__ att_s, const float* __restrict__ att_d,
    unsigned* __restrict__ h1h, float* __restrict__ a1s, float* __restrict__ a1d, int N)
{
  __shared__ __align__(16) _Float16 Xh[64 * XPAD];
  __shared__ __align__(16) _Float16 Wt[128 * XPAD];
  int t = threadIdx.x;
  const float4* W4 = (const float4*)W;
#pragma unroll
  for (int i = 0; i < 16; ++i) {
    int id = t + i * 256;
    int row = id >> 5, c0 = (id & 31) * 4;
    float4 wv = W4[id];
    Wt[(c0    ) * XPAD + row] = (_Float16)wv.x;
    Wt[(c0 + 1) * XPAD + row] = (_Float16)wv.y;
    Wt[(c0 + 2) * XPAD + row] = (_Float16)wv.z;
    Wt[(c0 + 3) * XPAD + row] = (_Float16)wv.w;
  }
  int row0 = blockIdx.x * 64;
  const float4* X4 = (const float4*)x;
#pragma unroll
  for (int i = 0; i < 8; ++i) {
    int id = t + i * 256;
    int r = id >> 5, c = id & 31;
    int gr = row0 + r;
    float4 v = (gr < N) ? X4[(size_t)gr * 32 + c] : make_float4(0.f, 0.f, 0.f, 0.f);
    unsigned p01 = (unsigned)h2i(__floats2half2_rn(v.x, v.y));
    unsigned p23 = (unsigned)h2i(__floats2half2_rn(v.z, v.w));
    *(uint2*)&Xh[r * XPAD + c * 4] = make_uint2(p01, p23);
  }
  __syncthreads();
  int w = t >> 6, l = t & 63;
  int m = l & 15, kg = l >> 4;
  f32x4 acc[8];
#pragma unroll
  for (int c = 0; c < 8; ++c) { acc[c][0] = 0.f; acc[c][1] = 0.f; acc[c][2] = 0.f; acc[c][3] = 0.f; }
#pragma unroll
  for (int ks = 0; ks < 4; ++ks) {
    f16x8 a = *(const f16x8*)&Xh[(w * 16 + m) * XPAD + ks * 32 + kg * 8];
#pragma unroll
    for (int c = 0; c < 8; ++c) {
      f16x8 bfr = *(const f16x8*)&Wt[(c * 16 + m) * XPAD + ks * 32 + kg * 8];
      acc[c] = __builtin_amdgcn_mfma_f32_16x16x32_f16(a, bfr, acc[c], 0, 0, 0);
    }
  }
#pragma unroll
  for (int c = 0; c < 8; ++c)
#pragma unroll
    for (int r = 0; r < 4; ++r)
      Xh[(w * 16 + kg * 4 + r) * XPAD + c * 16 + m] = (_Float16)acc[c][r];
  __syncthreads();
#pragma unroll
  for (int i = 0; i < 8; ++i) {
    int id = t + i * 256;
    int r = id >> 5, c4 = id & 31;
    int gr = row0 + r;
    uint2 pk = *(const uint2*)&Xh[r * XPAD + c4 * 4];
    float2 v01 = __half22float2(i2h((int)pk.x));
    float2 v23 = __half22float2(i2h((int)pk.y));
    int col = c4 * 4;
    float4 asv = *(const float4*)&att_s[col];
    float4 adv = *(const float4*)&att_d[col];
    float ps = v01.x * asv.x + v01.y * asv.y + v23.x * asv.z + v23.y * asv.w;
    float pd = v01.x * adv.x + v01.y * adv.y + v23.x * adv.z + v23.y * adv.w;
    ps += __shfl_xor(ps, 1); ps += __shfl_xor(ps, 2); ps += __shfl_xor(ps, 4); ps += __shfl_xor(ps, 8);
    pd += __shfl_xor(pd, 1); pd += __shfl_xor(pd, 2); pd += __shfl_xor(pd, 4); pd += __shfl_xor(pd, 8);
    if (gr < N) {
      *(uint2*)&h1h[(size_t)gr * 64 + c4 * 2] = pk;
      if ((t & 15) == 0) { int h = (t >> 4) & 1; a1s[gr * 2 + h] = ps; a1d[gr * 2 + h] = pd; }
    }
  }
}

// ====== Aggregate layer 1: FOUR nodes per wave (16-lane groups, uint4 = full 256B row) ======
__global__ __launch_bounds__(256) void k_agg1(
    const int* __restrict__ rowptr, const int* __restrict__ colx,
    const unsigned* __restrict__ h1h, const float* __restrict__ a1s,
    const float* __restrict__ a1d, const float* __restrict__ b1,
    unsigned* __restrict__ v1h, int N)
{
  int t = threadIdx.x;
  int w = t >> 6, lane = t & 63;
  int g = lane >> 4, q = lane & 15;
  bool hi = q >= 8;                    // feats 8q..8q+7 -> head = q>=8
  int n = blockIdx.x * 16 + w * 4 + g;
  bool act = n < N;
  float4 biasA = *(const float4*)&b1[q * 8];
  float4 biasB = *(const float4*)&b1[q * 8 + 4];
  int start = 0, end = 0;
  float2 ad = make_float2(0.f, 0.f);
  if (act) { start = rowptr[n]; end = rowptr[n + 1]; ad = *(const float2*)&a1d[n * 2]; }
  float se = 0.f;
  float4 accA = {0, 0, 0, 0}, accB = {0, 0, 0, 0};
  for (int base = start; base < end; base += 16) {
    int cnt = end - base; if (cnt > 16) cnt = 16;
    int sl = 0, epk = 0;
    if (q < cnt) {
      sl = colx[base + q];
      float2 av = *(const float2*)&a1s[sl * 2];
      float x0 = av.x + ad.x, x1 = av.y + ad.y;
      x0 = (x0 > 0.f) ? x0 : LEAKY * x0;
      x1 = (x1 > 0.f) ? x1 : LEAKY * x1;
      epk = h2i(__floats2half2_rn(__expf(x0), __expf(x1)));
    }
    int j = 0;
    if (cnt == 16) {
      int ss[16], ee[16];
#pragma unroll
      for (int k = 0; k < 16; ++k) { ss[k] = __shfl(sl, k, 16); ee[k] = __shfl(epk, k, 16); }
      uint4 rr[16];
#pragma unroll
      for (int k = 0; k < 16; ++k) rr[k] = *(const uint4*)&h1h[(size_t)ss[k] * 64 + q * 4];
#pragma unroll
      for (int k = 0; k < 16; ++k) {
        float2 ef = __half22float2(i2h(ee[k]));
        float wg = hi ? ef.y : ef.x;
        float2 r0 = __half22float2(i2h((int)rr[k].x));
        float2 r1 = __half22float2(i2h((int)rr[k].y));
        float2 r2 = __half22float2(i2h((int)rr[k].z));
        float2 r3 = __half22float2(i2h((int)rr[k].w));
        se += wg;
        accA.x = fmaf(wg, r0.x, accA.x); accA.y = fmaf(wg, r0.y, accA.y);
        accA.z = fmaf(wg, r1.x, accA.z); accA.w = fmaf(wg, r1.y, accA.w);
        accB.x = fmaf(wg, r2.x, accB.x); accB.y = fmaf(wg, r2.y, accB.y);
        accB.z = fmaf(wg, r3.x, accB.z); accB.w = fmaf(wg, r3.y, accB.w);
      }
      j = 16;
    }
    int lim8 = cnt & ~7;
    for (; j < lim8; j += 8) {
      int ss[8], ee[8];
#pragma unroll
      for (int k = 0; k < 8; ++k) { ss[k] = __shfl(sl, j + k, 16); ee[k] = __shfl(epk, j + k, 16); }
      uint4 rr[8];
#pragma unroll
      for (int k = 0; k < 8; ++k) rr[k] = *(const uint4*)&h1h[(size_t)ss[k] * 64 + q * 4];
#pragma unroll
      for (int k = 0; k < 8; ++k) {
        float2 ef = __half22float2(i2h(ee[k]));
        float wg = hi ? ef.y : ef.x;
        float2 r0 = __half22float2(i2h((int)rr[k].x));
        float2 r1 = __half22float2(i2h((int)rr[k].y));
        float2 r2 = __half22float2(i2h((int)rr[k].z));
        float2 r3 = __half22float2(i2h((int)rr[k].w));
        se += wg;
        accA.x = fmaf(wg, r0.x, accA.x); accA.y = fmaf(wg, r0.y, accA.y);
        accA.z = fmaf(wg, r1.x, accA.z); accA.w = fmaf(wg, r1.y, accA.w);
        accB.x = fmaf(wg, r2.x, accB.x); accB.y = fmaf(wg, r2.y, accB.y);
        accB.z = fmaf(wg, r3.x, accB.z); accB.w = fmaf(wg, r3.y, accB.w);
      }
    }
    for (; j < cnt; ++j) {
      int s0 = __shfl(sl, j, 16), e0 = __shfl(epk, j, 16);
      float2 ef = __half22float2(i2h(e0));
      float wg = hi ? ef.y : ef.x;
      uint4 rv = *(const uint4*)&h1h[(size_t)s0 * 64 + q * 4];
      float2 r0 = __half22float2(i2h((int)rv.x));
      float2 r1 = __half22float2(i2h((int)rv.y));
      float2 r2 = __half22float2(i2h((int)rv.z));
      float2 r3 = __half22float2(i2h((int)rv.w));
      se += wg;
      accA.x = fmaf(wg, r0.x, accA.x); accA.y = fmaf(wg, r0.y, accA.y);
      accA.z = fmaf(wg, r1.x, accA.z); accA.w = fmaf(wg, r1.y, accA.w);
      accB.x = fmaf(wg, r2.x, accB.x); accB.y = fmaf(wg, r2.y, accB.y);
      accB.z = fmaf(wg, r3.x, accB.z); accB.w = fmaf(wg, r3.y, accB.w);
    }
  }
  if (act) {
    float inv = 1.f / se;
    float4 oA, oB;
    oA.x = fmaf(accA.x, inv, biasA.x);
    oA.y = fmaf(accA.y, inv, biasA.y);
    oA.z = fmaf(accA.z, inv, biasA.z);
    oA.w = fmaf(accA.w, inv, biasA.w);
    oB.x = fmaf(accB.x, inv, biasB.x);
    oB.y = fmaf(accB.y, inv, biasB.y);
    oB.z = fmaf(accB.z, inv, biasB.z);
    oB.w = fmaf(accB.w, inv, biasB.w);
    unsigned p0 = (unsigned)h2i(__floats2half2_rn(oA.x, oA.y));
    unsigned p1 = (unsigned)h2i(__floats2half2_rn(oA.z, oA.w));
    unsigned p2 = (unsigned)h2i(__floats2half2_rn(oB.x, oB.y));
    unsigned p3 = (unsigned)h2i(__floats2half2_rn(oB.z, oB.w));
    *(uint4*)&v1h[(size_t)n * 64 + q * 4] = make_uint4(p0, p1, p2, p3);
  }
}

// ====== k_stats<UPR>: per-feature sum/sumsq over fp16-pair rows, 8-sliced ======
template<int UPR>
__global__ __launch_bounds__(256) void k_stats(const unsigned* __restrict__ vh,
                                               float* __restrict__ stats, int N)
{
  const int F = UPR * 2, RPB = 256 / UPR;
  int t = threadIdx.x;
  int q = t & (UPR - 1), rg = t / UPR;
  float s0 = 0.f, s1 = 0.f, q0 = 0.f, q1 = 0.f;
  for (int n = blockIdx.x * RPB + rg; n < N; n += 256 * RPB) {
    float2 vf = __half22float2(i2h((int)vh[(size_t)n * UPR + q]));
    s0 += vf.x; q0 += vf.x * vf.x;
    s1 += vf.y; q1 += vf.y * vf.y;
  }
  __shared__ float4 red[256];
  red[t] = make_float4(s0, s1, q0, q1);
  __syncthreads();
  if (t < UPR) {
    float4 a = red[t];
#pragma unroll
    for (int g2 = 1; g2 < RPB; ++g2) {
      float4 b = red[t + g2 * UPR];
      a.x += b.x; a.y += b.y; a.z += b.z; a.w += b.w;
    }
    int sl = (blockIdx.x & 7) * 2 * F;
    atomicAdd(&stats[sl + 2 * t], a.x);
    atomicAdd(&stats[sl + 2 * t + 1], a.y);
    atomicAdd(&stats[sl + F + 2 * t], a.z);
    atomicAdd(&stats[sl + F + 2 * t + 1], a.w);
  }
}

// ====== GEMM2 (MFMA): h2 = relu(bn(v1h)) @ W2, fp16 out ======
__global__ __launch_bounds__(256) void k_gemm2(
    const unsigned* __restrict__ v1h, const float* __restrict__ W2,
    const float* __restrict__ stats, const float* __restrict__ g1, const float* __restrict__ be1,
    const float* __restrict__ att_s, const float* __restrict__ att_d,
    unsigned* __restrict__ h2h, float* __restrict__ a2s, float* __restrict__ a2d,
    int N, float rcpN)
{
  __shared__ __align__(16) _Float16 Xh[64 * XPAD];
  __shared__ __align__(16) _Float16 Wt[64 * XPAD];
  __shared__ float kc[128], sc[128];
  int t = threadIdx.x;
  if (t < 128) {
    float su = 0.f, sq = 0.f;
#pragma unroll
    for (int s8 = 0; s8 < 8; ++s8) { su += stats[s8 * 256 + t]; sq += stats[s8 * 256 + 128 + t]; }
    float mu = su * rcpN;
    float var = sq * rcpN - mu * mu;
    float kk = g1[t] * rsqrtf(var + 1e-5f);
    kc[t] = kk; sc[t] = be1[t] - mu * kk;
  }
  const float4* W4 = (const float4*)W2;
#pragma unroll
  for (int i = 0; i < 8; ++i) {
    int id = t + i * 256;
    int row = id >> 4, c0 = (id & 15) * 4;
    float4 wv = W4[id];
    Wt[(c0    ) * XPAD + row] = (_Float16)wv.x;
    Wt[(c0 + 1) * XPAD + row] = (_Float16)wv.y;
    Wt[(c0 + 2) * XPAD + row] = (_Float16)wv.z;
    Wt[(c0 + 3) * XPAD + row] = (_Float16)wv.w;
  }
  __syncthreads();
  int row0 = blockIdx.x * 64;
#pragma unroll
  for (int i = 0; i < 8; ++i) {
    int id = t + i * 256;
    int r = id >> 5, c4 = id & 31;
    int gr = row0 + r;
    uint2 pv = (gr < N) ? *(const uint2*)&v1h[(size_t)gr * 64 + c4 * 2] : make_uint2(0, 0);
    float2 a01 = __half22float2(i2h((int)pv.x));
    float2 a23 = __half22float2(i2h((int)pv.y));
    int f0 = c4 * 4;
    float o0 = fmaxf(a01.x * kc[f0]     + sc[f0],     0.f);
    float o1 = fmaxf(a01.y * kc[f0 + 1] + sc[f0 + 1], 0.f);
    float o2 = fmaxf(a23.x * kc[f0 + 2] + sc[f0 + 2], 0.f);
    float o3 = fmaxf(a23.y * kc[f0 + 3] + sc[f0 + 3], 0.f);
    unsigned p01 = (unsigned)h2i(__floats2half2_rn(o0, o1));
    unsigned p23 = (unsigned)h2i(__floats2half2_rn(o2, o3));
    *(uint2*)&Xh[r * XPAD + c4 * 4] = make_uint2(p01, p23);
  }
  __syncthreads();
  int w = t >> 6, l = t & 63;
  int m = l & 15, kg = l >> 4;
  f32x4 acc[4];
#pragma unroll
  for (int c = 0; c < 4; ++c) { acc[c][0] = 0.f; acc[c][1] = 0.f; acc[c][2] = 0.f; acc[c][3] = 0.f; }
#pragma unroll
  for (int ks = 0; ks < 4; ++ks) {
    f16x8 a = *(const f16x8*)&Xh[(w * 16 + m) * XPAD + ks * 32 + kg * 8];
#pragma unroll
    for (int c = 0; c < 4; ++c) {
      f16x8 bfr = *(const f16x8*)&Wt[(c * 16 + m) * XPAD + ks * 32 + kg * 8];
      acc[c] = __builtin_amdgcn_mfma_f32_16x16x32_f16(a, bfr, acc[c], 0, 0, 0);
    }
  }
#pragma unroll
  for (int c = 0; c < 4; ++c)
#pragma unroll
    for (int r = 0; r < 4; ++r)
      Xh[(w * 16 + kg * 4 + r) * XPAD + c * 16 + m] = (_Float16)acc[c][r];
  __syncthreads();
#pragma unroll
  for (int i = 0; i < 4; ++i) {
    int id = t + i * 256;
    int r = id >> 4, c4 = id & 15;
    int gr = row0 + r;
    uint2 pk = *(const uint2*)&Xh[r * XPAD + c4 * 4];
    float2 v01 = __half22float2(i2h((int)pk.x));
    float2 v23 = __half22float2(i2h((int)pk.y));
    int col = c4 * 4;
    float4 asv = *(const float4*)&att_s[col];
    float4 adv = *(const float4*)&att_d[col];
    float ps = v01.x * asv.x + v01.y * asv.y + v23.x * asv.z + v23.y * asv.w;
    float pd = v01.x * adv.x + v01.y * adv.y + v23.x * adv.z + v23.y * adv.w;
    ps += __shfl_xor(ps, 1); ps += __shfl_xor(ps, 2); ps += __shfl_xor(ps, 4); ps += __shfl_xor(ps, 8);
    pd += __shfl_xor(pd, 1); pd += __shfl_xor(pd, 2); pd += __shfl_xor(pd, 4); pd += __shfl_xor(pd, 8);
    if (gr < N) {
      *(uint2*)&h2h[(size_t)gr * 32 + c4 * 2] = pk;
      if ((t & 15) == 0) { a2s[gr] = ps; a2d[gr] = pd; }
    }
  }
}

// ====== Aggregate layer 2: FOUR nodes per wave (16-lane groups, uint2 feats) ======
__global__ __launch_bounds__(256) void k_agg2(
    const int* __restrict__ rowptr, const int* __restrict__ colx,
    const unsigned* __restrict__ h2h, const float* __restrict__ a2s,
    const float* __restrict__ a2d, const float* __restrict__ b2,
    unsigned* __restrict__ v2h, int N)
{
  int t = threadIdx.x;
  int w = t >> 6, lane = t & 63;
  int g = lane >> 4, q = lane & 15;
  int n = blockIdx.x * 16 + w * 4 + g;
  bool act = n < N;
  float4 bias = *(const float4*)&b2[q * 4];
  int start = 0, end = 0;
  float ad = 0.f;
  if (act) { start = rowptr[n]; end = rowptr[n + 1]; ad = a2d[n]; }
  float se = 0.f;
  float4 acc = {0, 0, 0, 0};
  for (int base = start; base < end; base += 16) {
    int cnt = end - base; if (cnt > 16) cnt = 16;
    int sl = 0; float ev = 0.f;
    if (q < cnt) {
      sl = colx[base + q];
      float av = a2s[sl] + ad;
      av = (av > 0.f) ? av : LEAKY * av;
      ev = __expf(av);
    }
    int j = 0;
    if (cnt == 16) {
      int ss[16]; float ee[16];
#pragma unroll
      for (int k = 0; k < 16; ++k) { ss[k] = __shfl(sl, k, 16); ee[k] = __shfl(ev, k, 16); }
      uint2 rr[16];
#pragma unroll
      for (int k = 0; k < 16; ++k) rr[k] = *(const uint2*)&h2h[(size_t)ss[k] * 32 + q * 2];
#pragma unroll
      for (int k = 0; k < 16; ++k) {
        float2 r01 = __half22float2(i2h((int)rr[k].x));
        float2 r23 = __half22float2(i2h((int)rr[k].y));
        se += ee[k];
        acc.x = fmaf(ee[k], r01.x, acc.x);
        acc.y = fmaf(ee[k], r01.y, acc.y);
        acc.z = fmaf(ee[k], r23.x, acc.z);
        acc.w = fmaf(ee[k], r23.y, acc.w);
      }
      j = 16;
    }
    int lim8 = cnt & ~7;
    for (; j < lim8; j += 8) {
      int ss[8]; float ee[8];
#pragma unroll
      for (int k = 0; k < 8; ++k) { ss[k] = __shfl(sl, j + k, 16); ee[k] = __shfl(ev, j + k, 16); }
      uint2 rr[8];
#pragma unroll
      for (int k = 0; k < 8; ++k) rr[k] = *(const uint2*)&h2h[(size_t)ss[k] * 32 + q * 2];
#pragma unroll
      for (int k = 0; k < 8; ++k) {
        float2 r01 = __half22float2(i2h((int)rr[k].x));
        float2 r23 = __half22float2(i2h((int)rr[k].y));
        se += ee[k];
        acc.x = fmaf(ee[k], r01.x, acc.x);
        acc.y = fmaf(ee[k], r01.y, acc.y);
        acc.z = fmaf(ee[k], r23.x, acc.z);
        acc.w = fmaf(ee[k], r23.y, acc.w);
      }
    }
    for (; j < cnt; ++j) {
      int s0 = __shfl(sl, j, 16);
      float e0 = __shfl(ev, j, 16);
      uint2 rv = *(const uint2*)&h2h[(size_t)s0 * 32 + q * 2];
      float2 r01 = __half22float2(i2h((int)rv.x));
      float2 r23 = __half22float2(i2h((int)rv.y));
      se += e0;
      acc.x = fmaf(e0, r01.x, acc.x);
      acc.y = fmaf(e0, r01.y, acc.y);
      acc.z = fmaf(e0, r23.x, acc.z);
      acc.w = fmaf(e0, r23.y, acc.w);
    }
  }
  if (act) {
    float inv = 1.f / se;
    float4 o;
    o.x = fmaf(acc.x, inv, bias.x);
    o.y = fmaf(acc.y, inv, bias.y);
    o.z = fmaf(acc.z, inv, bias.z);
    o.w = fmaf(acc.w, inv, bias.w);
    unsigned p01 = (unsigned)h2i(__floats2half2_rn(o.x, o.y));
    unsigned p23 = (unsigned)h2i(__floats2half2_rn(o.z, o.w));
    *(uint2*)&v2h[(size_t)n * 32 + q * 2] = make_uint2(p01, p23);
  }
}

// ====== Final: out = relu(bn(v2h)) @ linW + linb, 2 nodes/wave, shared BN ======
__global__ __launch_bounds__(256) void k_out(
    const unsigned* __restrict__ v2h, const float* __restrict__ stats,
    const float* __restrict__ g2, const float* __restrict__ be2,
    const float* __restrict__ linW, const float* __restrict__ linb,
    float* __restrict__ out, int N, float rcpN)
{
  __shared__ float kc[64], sc[64], lw[64];
  int t = threadIdx.x;
  if (t < 64) {
    float su = 0.f, sq = 0.f;
#pragma unroll
    for (int s8 = 0; s8 < 8; ++s8) { su += stats[s8 * 128 + t]; sq += stats[s8 * 128 + 64 + t]; }
    float mu = su * rcpN;
    float var = sq * rcpN - mu * mu;
    float kk = g2[t] * rsqrtf(var + 1e-5f);
    kc[t] = kk; sc[t] = be2[t] - mu * kk; lw[t] = linW[t];
  }
  __syncthreads();
  int w = t >> 6, lane = t & 63, g = lane >> 5, q = lane & 31;
  int n = blockIdx.x * 8 + w * 2 + g;
  if (n >= N) return;
  unsigned uv = v2h[(size_t)n * 32 + q];
  float2 vf = __half22float2(i2h((int)uv));
  float h0 = fmaxf(vf.x * kc[2 * q] + sc[2 * q], 0.f);
  float h1 = fmaxf(vf.y * kc[2 * q + 1] + sc[2 * q + 1], 0.f);
  float p = fmaf(h0, lw[2 * q], h1 * lw[2 * q + 1]);
#pragma unroll
  for (int off = 16; off; off >>= 1) p += __shfl_xor(p, off, 32);
  if (q == 0) out[n] = p + linb[0];
}

extern "C" void kernel_launch(void* const* d_in, const int* in_sizes, int n_in,
                              void* d_out, int out_size, void* d_ws, size_t ws_size,
                              hipStream_t stream)
{
  const float* x    = (const float*)d_in[0];
  const int*   ei   = (const int*)d_in[1];
  const float* W1   = (const float*)d_in[2];
  const float* as1  = (const float*)d_in[3];
  const float* ad1  = (const float*)d_in[4];
  const float* b1   = (const float*)d_in[5];
  const float* g1   = (const float*)d_in[6];
  const float* be1  = (const float*)d_in[7];
  const float* W2   = (const float*)d_in[8];
  const float* as2  = (const float*)d_in[9];
  const float* ad2  = (const float*)d_in[10];
  const float* b2   = (const float*)d_in[11];
  const float* g2   = (const float*)d_in[12];
  const float* be2  = (const float*)d_in[13];
  const float* linW = (const float*)d_in[14];
  const float* linb = (const float*)d_in[15];
  float* out = (float*)d_out;

  int N = in_sizes[0] / 128;
  int E = in_sizes[1] / 2;
  int Etot = E + N;
  float rcpN = 1.f / (float)N;
  int PB = (N + 127) / 128;

  float* ws = (float*)d_ws;
  size_t o = 0;
  float* H1HF = ws + o; o += (size_t)N * 64;
  float* V1HF = ws + o; o += (size_t)N * 64;
  float* A1S  = ws + o; o += (size_t)N * 2;
  float* A1D  = ws + o; o += (size_t)N * 2;
  float* A2S  = ws + o; o += N;
  float* A2D  = ws + o; o += N;
  float* ST1  = ws + o; o += 8 * 256;          // zero region start
  float* ST2  = ws + o; o += 8 * 128;
  int* GBCNT  = (int*)(ws + o); o += MAXB;     // zero region end
  int* PBASE  = (int*)(ws + o); o += MAXB + 1;
  int* GCUR   = (int*)(ws + o); o += MAXB;
  int* ROWPTR = (int*)(ws + o); o += (size_t)N + 1;
  int* COL    = (int*)(ws + o); o += (size_t)Etot;
  int2* PAIRS = (int2*)(ws + o); o += (size_t)E * 2;
  unsigned* H1H = (unsigned*)H1HF;
  unsigned* H2H = (unsigned*)H1HF;
  unsigned* V1H = (unsigned*)V1HF;
  unsigned* V2H = (unsigned*)V1HF;

  hipMemsetAsync(ST1, 0, (3072 + MAXB) * 4, stream);

  int gb  = (N + 63) / 64;
  int bh  = (E + 2047) / 2048;
  int pt  = (E + 4095) / 4096;
  int ab1 = (N + 15) / 16;
  int ab2 = (N + 15) / 16;
  int ob  = (N + 7) / 8;

  k_bhist<<<bh, 256, 0, stream>>>(ei, GBCNT, E, PB);
  k_bscan<<<1, 512, 0, stream>>>(GBCNT, PBASE, GCUR, PB);
  k_part<<<pt, 256, 0, stream>>>(ei, GCUR, PAIRS, E, PB);
  k_fine<<<PB, 256, 0, stream>>>(PAIRS, PBASE, ROWPTR, COL, N);
  k_gemm1<<<gb, 256, 0, stream>>>(x, W1, as1, ad1, H1H, A1S, A1D, N);
  k_agg1<<<ab1, 256, 0, stream>>>(ROWPTR, COL, H1H, A1S, A1D, b1, V1H, N);
  k_stats<64><<<256, 256, 0, stream>>>(V1H, ST1, N);
  k_gemm2<<<gb, 256, 0, stream>>>(V1H, W2, ST1, g1, be1, as2, ad2, H2H, A2S, A2D, N, rcpN);
  k_agg2<<<ab2, 256, 0, stream>>>(ROWPTR, COL, H2H, A2S, A2D, b2, V2H, N);
  k_stats<32><<<256, 256, 0, stream>>>(V2H, ST2, N);
  k_out<<<ob, 256, 0, stream>>>(V2H, ST2, g2, be2, linW, linb, out, N, rcpN);
}

// Round 14
// 167.207 us; speedup vs baseline: 1.0736x; 1.0736x over previous
//
#include <hip/hip_runtime.h>
#include <hip/hip_fp16.h>
#include <math.h>

#define LEAKY 0.2f
#define XPAD 136   // 128 + 8 halves row pad
#define MAXB 512   // max dst-buckets (128 nodes each; N<=65536)

typedef _Float16 f16x8 __attribute__((ext_vector_type(8)));
typedef float f32x4 __attribute__((ext_vector_type(4)));

__device__ inline int h2i(__half2 h) { union { __half2 h; int i; } u; u.h = h; return u.i; }
__device__ inline __half2 i2h(int i) { union { __half2 h; int i; } u; u.i = i; return u.h; }

// ====== CSR build: bucketed partition ======
__global__ __launch_bounds__(256) void k_bhist(const int* __restrict__ ei,
                                               int* __restrict__ gbcnt, int E, int PB)
{
  __shared__ int lh[MAXB];
  int t = threadIdx.x;
  for (int i = t; i < PB; i += 256) lh[i] = 0;
  __syncthreads();
  int base = blockIdx.x * 2048;
#pragma unroll
  for (int k = 0; k < 8; ++k) {
    int idx = base + t + k * 256;
    if (idx < E) atomicAdd(&lh[ei[E + idx] >> 7], 1);
  }
  __syncthreads();
  for (int i = t; i < PB; i += 256) if (lh[i]) atomicAdd(&gbcnt[i], lh[i]);
}

__global__ __launch_bounds__(512) void k_bscan(const int* __restrict__ gbcnt,
                                               int* __restrict__ pbase,
                                               int* __restrict__ gcur, int PB)
{
  __shared__ int ls[512];
  int t = threadIdx.x;
  int v = (t < PB) ? gbcnt[t] : 0;
  ls[t] = v;
  __syncthreads();
  for (int off = 1; off < 512; off <<= 1) {
    int u = (t >= off) ? ls[t - off] : 0;
    __syncthreads();
    ls[t] += u;
    __syncthreads();
  }
  int excl = ls[t] - v;
  if (t <= PB) pbase[t] = excl;
  if (t < PB) gcur[t] = excl;
}

__global__ __launch_bounds__(256) void k_part(const int* __restrict__ ei,
                                              int* __restrict__ gcur,
                                              int2* __restrict__ pairs, int E, int PB)
{
  __shared__ int lcnt[MAXB], lbase[MAXB];
  int t = threadIdx.x;
  for (int i = t; i < PB; i += 256) lcnt[i] = 0;
  __syncthreads();
  int base = blockIdx.x * 4096;
  int lsrc[16], ldst[16], lp[16];
#pragma unroll
  for (int k = 0; k < 16; ++k) {
    int idx = base + t + k * 256;
    lp[k] = -1;
    if (idx < E) {
      int s = ei[idx], d = ei[E + idx];
      lsrc[k] = s; ldst[k] = d;
      int b = d >> 7;
      int p = atomicAdd(&lcnt[b], 1);
      lp[k] = (p << 10) | b;
    }
  }
  __syncthreads();
  for (int b = t; b < PB; b += 256) lbase[b] = atomicAdd(&gcur[b], lcnt[b]);
  __syncthreads();
#pragma unroll
  for (int k = 0; k < 16; ++k) {
    if (lp[k] >= 0) {
      int b = lp[k] & 1023, p = lp[k] >> 10;
      pairs[lbase[b] + p] = make_int2(lsrc[k], ldst[k]);
    }
  }
}

__global__ __launch_bounds__(256) void k_fine(const int2* __restrict__ pairs,
                                              const int* __restrict__ pbase,
                                              int* __restrict__ rowptr,
                                              int* __restrict__ colx, int N)
{
  __shared__ int ldeg[128], lcur[128];
  int b = blockIdx.x, t = threadIdx.x;
  int nbase = b << 7;
  int nbn = N - nbase; if (nbn > 128) nbn = 128;
  if (t < 128) ldeg[t] = (t < nbn) ? 1 : 0;
  __syncthreads();
  int e0 = pbase[b], e1 = pbase[b + 1];
  for (int e = e0 + t; e < e1; e += 256) atomicAdd(&ldeg[pairs[e].y - nbase], 1);
  __syncthreads();
  int myv = (t < 128) ? ldeg[t] : 0;
  for (int off = 1; off < 128; off <<= 1) {
    int u = (t < 128 && t >= off) ? ldeg[t - off] : 0;
    __syncthreads();
    if (t < 128) ldeg[t] += u;
    __syncthreads();
  }
  int colx0 = e0 + nbase;
  if (t < 128) {
    int excl = ldeg[t] - myv;
    lcur[t] = colx0 + excl;
    int idx = nbase + t;
    if (idx <= N) rowptr[idx] = colx0 + excl;
  }
  __syncthreads();
  for (int e = e0 + t; e < e1; e += 256) {
    int2 p = pairs[e];
    int pos = atomicAdd(&lcur[p.y - nbase], 1);
    colx[pos] = p.x;
  }
  if (t < nbn) {
    int pos = atomicAdd(&lcur[t], 1);
    colx[pos] = nbase + t;
  }
}

// ====== GEMM1 (MFMA): h1 = x @ W1, fp16 out, fused att dots ======
__global__ __launch_bounds__(256) void k_gemm1(
    const float* __restrict__ x, const float* __restrict__ W,
    const float* __restrict__ att_s, const float* __restrict__ att_d,
    unsigned* __restrict__ h1h, float* __restrict__ a1s, float* __restrict__ a1d, int N)
{
  __shared__ __align__(16) _Float16 Xh[64 * XPAD];
  __shared__ __align__(16) _Float16 Wt[128 * XPAD];
  int t = threadIdx.x;
  const float4* W4 = (const float4*)W;
#pragma unroll
  for (int i = 0; i < 16; ++i) {
    int id = t + i * 256;
    int row = id >> 5, c0 = (id & 31) * 4;
    float4 wv = W4[id];
    Wt[(c0    ) * XPAD + row] = (_Float16)wv.x;
    Wt[(c0 + 1) * XPAD + row] = (_Float16)wv.y;
    Wt[(c0 + 2) * XPAD + row] = (_Float16)wv.z;
    Wt[(c0 + 3) * XPAD + row] = (_Float16)wv.w;
  }
  int row0 = blockIdx.x * 64;
  const float4* X4 = (const float4*)x;
#pragma unroll
  for (int i = 0; i < 8; ++i) {
    int id = t + i * 256;
    int r = id >> 5, c = id & 31;
    int gr = row0 + r;
    float4 v = (gr < N) ? X4[(size_t)gr * 32 + c] : make_float4(0.f, 0.f, 0.f, 0.f);
    unsigned p01 = (unsigned)h2i(__floats2half2_rn(v.x, v.y));
    unsigned p23 = (unsigned)h2i(__floats2half2_rn(v.z, v.w));
    *(uint2*)&Xh[r * XPAD + c * 4] = make_uint2(p01, p23);
  }
  __syncthreads();
  int w = t >> 6, l = t & 63;
  int m = l & 15, kg = l >> 4;
  f32x4 acc[8];
#pragma unroll
  for (int c = 0; c < 8; ++c) { acc[c][0] = 0.f; acc[c][1] = 0.f; acc[c][2] = 0.f; acc[c][3] = 0.f; }
#pragma unroll
  for (int ks = 0; ks < 4; ++ks) {
    f16x8 a = *(const f16x8*)&Xh[(w * 16 + m) * XPAD + ks * 32 + kg * 8];
#pragma unroll
    for (int c = 0; c < 8; ++c) {
      f16x8 bfr = *(const f16x8*)&Wt[(c * 16 + m) * XPAD + ks * 32 + kg * 8];
      acc[c] = __builtin_amdgcn_mfma_f32_16x16x32_f16(a, bfr, acc[c], 0, 0, 0);
    }
  }
#pragma unroll
  for (int c = 0; c < 8; ++c)
#pragma unroll
    for (int r = 0; r < 4; ++r)
      Xh[(w * 16 + kg * 4 + r) * XPAD + c * 16 + m] = (_Float16)acc[c][r];
  __syncthreads();
#pragma unroll
  for (int i = 0; i < 8; ++i) {
    int id = t + i * 256;
    int r = id >> 5, c4 = id & 31;
    int gr = row0 + r;
    uint2 pk = *(const uint2*)&Xh[r * XPAD + c4 * 4];
    float2 v01 = __half22float2(i2h((int)pk.x));
    float2 v23 = __half22float2(i2h((int)pk.y));
    int col = c4 * 4;
    float4 asv = *(const float4*)&att_s[col];
    float4 adv = *(const float4*)&att_d[col];
    float ps = v01.x * asv.x + v01.y * asv.y + v23.x * asv.z + v23.y * asv.w;
    float pd = v01.x * adv.x + v01.y * adv.y + v23.x * adv.z + v23.y * adv.w;
    ps += __shfl_xor(ps, 1); ps += __shfl_xor(ps, 2); ps += __shfl_xor(ps, 4); ps += __shfl_xor(ps, 8);
    pd += __shfl_xor(pd, 1); pd += __shfl_xor(pd, 2); pd += __shfl_xor(pd, 4); pd += __shfl_xor(pd, 8);
    if (gr < N) {
      *(uint2*)&h1h[(size_t)gr * 64 + c4 * 2] = pk;
      if ((t & 15) == 0) { int h = (t >> 4) & 1; a1s[gr * 2 + h] = ps; a1d[gr * 2 + h] = pd; }
    }
  }
}

// ====== Aggregate layer 1: FOUR nodes/wave (16-lane groups, uint4 row), fused BN stats ======
__global__ __launch_bounds__(256) void k_agg1(
    const int* __restrict__ rowptr, const int* __restrict__ colx,
    const unsigned* __restrict__ h1h, const float* __restrict__ a1s,
    const float* __restrict__ a1d, const float* __restrict__ b1,
    unsigned* __restrict__ v1h, float* __restrict__ stats, int N)
{
  int t = threadIdx.x;
  int w = t >> 6, lane = t & 63;
  int g = lane >> 4, q = lane & 15;
  bool hi = q >= 8;                    // feats 8q..8q+7 -> head = q>=8
  int n = blockIdx.x * 16 + w * 4 + g;
  bool act = n < N;
  float4 biasA = *(const float4*)&b1[q * 8];
  float4 biasB = *(const float4*)&b1[q * 8 + 4];
  int start = 0, end = 0;
  float2 ad = make_float2(0.f, 0.f);
  if (act) { start = rowptr[n]; end = rowptr[n + 1]; ad = *(const float2*)&a1d[n * 2]; }
  float se = 0.f;
  float4 accA = {0, 0, 0, 0}, accB = {0, 0, 0, 0};
  for (int base = start; base < end; base += 16) {
    int cnt = end - base; if (cnt > 16) cnt = 16;
    int sl = 0, epk = 0;
    if (q < cnt) {
      sl = colx[base + q];
      float2 av = *(const float2*)&a1s[sl * 2];
      float x0 = av.x + ad.x, x1 = av.y + ad.y;
      x0 = (x0 > 0.f) ? x0 : LEAKY * x0;
      x1 = (x1 > 0.f) ? x1 : LEAKY * x1;
      epk = h2i(__floats2half2_rn(__expf(x0), __expf(x1)));
    }
    int j = 0;
    if (cnt == 16) {
      int ss[16], ee[16];
#pragma unroll
      for (int k = 0; k < 16; ++k) { ss[k] = __shfl(sl, k, 16); ee[k] = __shfl(epk, k, 16); }
      uint4 rr[16];
#pragma unroll
      for (int k = 0; k < 16; ++k) rr[k] = *(const uint4*)&h1h[(size_t)ss[k] * 64 + q * 4];
#pragma unroll
      for (int k = 0; k < 16; ++k) {
        float2 ef = __half22float2(i2h(ee[k]));
        float wg = hi ? ef.y : ef.x;
        float2 r0 = __half22float2(i2h((int)rr[k].x));
        float2 r1 = __half22float2(i2h((int)rr[k].y));
        float2 r2 = __half22float2(i2h((int)rr[k].z));
        float2 r3 = __half22float2(i2h((int)rr[k].w));
        se += wg;
        accA.x = fmaf(wg, r0.x, accA.x); accA.y = fmaf(wg, r0.y, accA.y);
        accA.z = fmaf(wg, r1.x, accA.z); accA.w = fmaf(wg, r1.y, accA.w);
        accB.x = fmaf(wg, r2.x, accB.x); accB.y = fmaf(wg, r2.y, accB.y);
        accB.z = fmaf(wg, r3.x, accB.z); accB.w = fmaf(wg, r3.y, accB.w);
      }
      j = 16;
    }
    int lim8 = cnt & ~7;
    for (; j < lim8; j += 8) {
      int ss[8], ee[8];
#pragma unroll
      for (int k = 0; k < 8; ++k) { ss[k] = __shfl(sl, j + k, 16); ee[k] = __shfl(epk, j + k, 16); }
      uint4 rr[8];
#pragma unroll
      for (int k = 0; k < 8; ++k) rr[k] = *(const uint4*)&h1h[(size_t)ss[k] * 64 + q * 4];
#pragma unroll
      for (int k = 0; k < 8; ++k) {
        float2 ef = __half22float2(i2h(ee[k]));
        float wg = hi ? ef.y : ef.x;
        float2 r0 = __half22float2(i2h((int)rr[k].x));
        float2 r1 = __half22float2(i2h((int)rr[k].y));
        float2 r2 = __half22float2(i2h((int)rr[k].z));
        float2 r3 = __half22float2(i2h((int)rr[k].w));
        se += wg;
        accA.x = fmaf(wg, r0.x, accA.x); accA.y = fmaf(wg, r0.y, accA.y);
        accA.z = fmaf(wg, r1.x, accA.z); accA.w = fmaf(wg, r1.y, accA.w);
        accB.x = fmaf(wg, r2.x, accB.x); accB.y = fmaf(wg, r2.y, accB.y);
        accB.z = fmaf(wg, r3.x, accB.z); accB.w = fmaf(wg, r3.y, accB.w);
      }
    }
    for (; j < cnt; ++j) {
      int s0 = __shfl(sl, j, 16), e0 = __shfl(epk, j, 16);
      float2 ef = __half22float2(i2h(e0));
      float wg = hi ? ef.y : ef.x;
      uint4 rv = *(const uint4*)&h1h[(size_t)s0 * 64 + q * 4];
      float2 r0 = __half22float2(i2h((int)rv.x));
      float2 r1 = __half22float2(i2h((int)rv.y));
      float2 r2 = __half22float2(i2h((int)rv.z));
      float2 r3 = __half22float2(i2h((int)rv.w));
      se += wg;
      accA.x = fmaf(wg, r0.x, accA.x); accA.y = fmaf(wg, r0.y, accA.y);
      accA.z = fmaf(wg, r1.x, accA.z); accA.w = fmaf(wg, r1.y, accA.w);
      accB.x = fmaf(wg, r2.x, accB.x); accB.y = fmaf(wg, r2.y, accB.y);
      accB.z = fmaf(wg, r3.x, accB.z); accB.w = fmaf(wg, r3.y, accB.w);
    }
  }
  float4 oA = {0,0,0,0}, oB = {0,0,0,0};
  if (act) {
    float inv = 1.f / se;
    oA.x = fmaf(accA.x, inv, biasA.x);
    oA.y = fmaf(accA.y, inv, biasA.y);
    oA.z = fmaf(accA.z, inv, biasA.z);
    oA.w = fmaf(accA.w, inv, biasA.w);
    oB.x = fmaf(accB.x, inv, biasB.x);
    oB.y = fmaf(accB.y, inv, biasB.y);
    oB.z = fmaf(accB.z, inv, biasB.z);
    oB.w = fmaf(accB.w, inv, biasB.w);
    unsigned p0 = (unsigned)h2i(__floats2half2_rn(oA.x, oA.y));
    unsigned p1 = (unsigned)h2i(__floats2half2_rn(oA.z, oA.w));
    unsigned p2 = (unsigned)h2i(__floats2half2_rn(oB.x, oB.y));
    unsigned p3 = (unsigned)h2i(__floats2half2_rn(oB.z, oB.w));
    *(uint4*)&v1h[(size_t)n * 64 + q * 4] = make_uint4(p0, p1, p2, p3);
  }
  // fused BN stats: lane holds feats 8q..8q+7 (A: 0-3, B: 4-7)
  __shared__ float redS[4][64][8], redQ[4][64][8];
#pragma unroll
  for (int j2 = 0; j2 < 4; ++j2) {
    redS[w][lane][j2]     = (&oA.x)[j2];
    redS[w][lane][4 + j2] = (&oB.x)[j2];
    redQ[w][lane][j2]     = (&oA.x)[j2] * (&oA.x)[j2];
    redQ[w][lane][4 + j2] = (&oB.x)[j2] * (&oB.x)[j2];
  }
  __syncthreads();
  if (t < 128) {
    int qq = t >> 3, jj = t & 7;      // feature f = 8*qq + jj
    float s = 0.f, sq = 0.f;
#pragma unroll
    for (int w2 = 0; w2 < 4; ++w2)
#pragma unroll
      for (int g2 = 0; g2 < 4; ++g2) {
        s  += redS[w2][g2 * 16 + qq][jj];
        sq += redQ[w2][g2 * 16 + qq][jj];
      }
    int sl8 = (blockIdx.x & 7) * 256;
    atomicAdd(&stats[sl8 + t], s);
    atomicAdd(&stats[sl8 + 128 + t], sq);
  }
}

// ====== GEMM2 (MFMA): h2 = relu(bn(v1h)) @ W2, fp16 out ======
__global__ __launch_bounds__(256) void k_gemm2(
    const unsigned* __restrict__ v1h, const float* __restrict__ W2,
    const float* __restrict__ stats, const float* __restrict__ g1, const float* __restrict__ be1,
    const float* __restrict__ att_s, const float* __restrict__ att_d,
    unsigned* __restrict__ h2h, float* __restrict__ a2s, float* __restrict__ a2d,
    int N, float rcpN)
{
  __shared__ __align__(16) _Float16 Xh[64 * XPAD];
  __shared__ __align__(16) _Float16 Wt[64 * XPAD];
  __shared__ float kc[128], sc[128];
  int t = threadIdx.x;
  if (t < 128) {
    float su = 0.f, sq = 0.f;
#pragma unroll
    for (int s8 = 0; s8 < 8; ++s8) { su += stats[s8 * 256 + t]; sq += stats[s8 * 256 + 128 + t]; }
    float mu = su * rcpN;
    float var = sq * rcpN - mu * mu;
    float kk = g1[t] * rsqrtf(var + 1e-5f);
    kc[t] = kk; sc[t] = be1[t] - mu * kk;
  }
  const float4* W4 = (const float4*)W2;
#pragma unroll
  for (int i = 0; i < 8; ++i) {
    int id = t + i * 256;
    int row = id >> 4, c0 = (id & 15) * 4;
    float4 wv = W4[id];
    Wt[(c0    ) * XPAD + row] = (_Float16)wv.x;
    Wt[(c0 + 1) * XPAD + row] = (_Float16)wv.y;
    Wt[(c0 + 2) * XPAD + row] = (_Float16)wv.z;
    Wt[(c0 + 3) * XPAD + row] = (_Float16)wv.w;
  }
  __syncthreads();
  int row0 = blockIdx.x * 64;
#pragma unroll
  for (int i = 0; i < 8; ++i) {
    int id = t + i * 256;
    int r = id >> 5, c4 = id & 31;
    int gr = row0 + r;
    uint2 pv = (gr < N) ? *(const uint2*)&v1h[(size_t)gr * 64 + c4 * 2] : make_uint2(0, 0);
    float2 a01 = __half22float2(i2h((int)pv.x));
    float2 a23 = __half22float2(i2h((int)pv.y));
    int f0 = c4 * 4;
    float o0 = fmaxf(a01.x * kc[f0]     + sc[f0],     0.f);
    float o1 = fmaxf(a01.y * kc[f0 + 1] + sc[f0 + 1], 0.f);
    float o2 = fmaxf(a23.x * kc[f0 + 2] + sc[f0 + 2], 0.f);
    float o3 = fmaxf(a23.y * kc[f0 + 3] + sc[f0 + 3], 0.f);
    unsigned p01 = (unsigned)h2i(__floats2half2_rn(o0, o1));
    unsigned p23 = (unsigned)h2i(__floats2half2_rn(o2, o3));
    *(uint2*)&Xh[r * XPAD + c4 * 4] = make_uint2(p01, p23);
  }
  __syncthreads();
  int w = t >> 6, l = t & 63;
  int m = l & 15, kg = l >> 4;
  f32x4 acc[4];
#pragma unroll
  for (int c = 0; c < 4; ++c) { acc[c][0] = 0.f; acc[c][1] = 0.f; acc[c][2] = 0.f; acc[c][3] = 0.f; }
#pragma unroll
  for (int ks = 0; ks < 4; ++ks) {
    f16x8 a = *(const f16x8*)&Xh[(w * 16 + m) * XPAD + ks * 32 + kg * 8];
#pragma unroll
    for (int c = 0; c < 4; ++c) {
      f16x8 bfr = *(const f16x8*)&Wt[(c * 16 + m) * XPAD + ks * 32 + kg * 8];
      acc[c] = __builtin_amdgcn_mfma_f32_16x16x32_f16(a, bfr, acc[c], 0, 0, 0);
    }
  }
#pragma unroll
  for (int c = 0; c < 4; ++c)
#pragma unroll
    for (int r = 0; r < 4; ++r)
      Xh[(w * 16 + kg * 4 + r) * XPAD + c * 16 + m] = (_Float16)acc[c][r];
  __syncthreads();
#pragma unroll
  for (int i = 0; i < 4; ++i) {
    int id = t + i * 256;
    int r = id >> 4, c4 = id & 15;
    int gr = row0 + r;
    uint2 pk = *(const uint2*)&Xh[r * XPAD + c4 * 4];
    float2 v01 = __half22float2(i2h((int)pk.x));
    float2 v23 = __half22float2(i2h((int)pk.y));
    int col = c4 * 4;
    float4 asv = *(const float4*)&att_s[col];
    float4 adv = *(const float4*)&att_d[col];
    float ps = v01.x * asv.x + v01.y * asv.y + v23.x * asv.z + v23.y * asv.w;
    float pd = v01.x * adv.x + v01.y * adv.y + v23.x * adv.z + v23.y * adv.w;
    ps += __shfl_xor(ps, 1); ps += __shfl_xor(ps, 2); ps += __shfl_xor(ps, 4); ps += __shfl_xor(ps, 8);
    pd += __shfl_xor(pd, 1); pd += __shfl_xor(pd, 2); pd += __shfl_xor(pd, 4); pd += __shfl_xor(pd, 8);
    if (gr < N) {
      *(uint2*)&h2h[(size_t)gr * 32 + c4 * 2] = pk;
      if ((t & 15) == 0) { a2s[gr] = ps; a2d[gr] = pd; }
    }
  }
}

// ====== Aggregate layer 2: FOUR nodes/wave (16-lane groups, uint2 feats), fused stats ======
__global__ __launch_bounds__(256) void k_agg2(
    const int* __restrict__ rowptr, const int* __restrict__ colx,
    const unsigned* __restrict__ h2h, const float* __restrict__ a2s,
    const float* __restrict__ a2d, const float* __restrict__ b2,
    unsigned* __restrict__ v2h, float* __restrict__ stats, int N)
{
  int t = threadIdx.x;
  int w = t >> 6, lane = t & 63;
  int g = lane >> 4, q = lane & 15;
  int n = blockIdx.x * 16 + w * 4 + g;
  bool act = n < N;
  float4 bias = *(const float4*)&b2[q * 4];
  int start = 0, end = 0;
  float ad = 0.f;
  if (act) { start = rowptr[n]; end = rowptr[n + 1]; ad = a2d[n]; }
  float se = 0.f;
  float4 acc = {0, 0, 0, 0};
  for (int base = start; base < end; base += 16) {
    int cnt = end - base; if (cnt > 16) cnt = 16;
    int sl = 0; float ev = 0.f;
    if (q < cnt) {
      sl = colx[base + q];
      float av = a2s[sl] + ad;
      av = (av > 0.f) ? av : LEAKY * av;
      ev = __expf(av);
    }
    int j = 0;
    if (cnt == 16) {
      int ss[16]; float ee[16];
#pragma unroll
      for (int k = 0; k < 16; ++k) { ss[k] = __shfl(sl, k, 16); ee[k] = __shfl(ev, k, 16); }
      uint2 rr[16];
#pragma unroll
      for (int k = 0; k < 16; ++k) rr[k] = *(const uint2*)&h2h[(size_t)ss[k] * 32 + q * 2];
#pragma unroll
      for (int k = 0; k < 16; ++k) {
        float2 r01 = __half22float2(i2h((int)rr[k].x));
        float2 r23 = __half22float2(i2h((int)rr[k].y));
        se += ee[k];
        acc.x = fmaf(ee[k], r01.x, acc.x);
        acc.y = fmaf(ee[k], r01.y, acc.y);
        acc.z = fmaf(ee[k], r23.x, acc.z);
        acc.w = fmaf(ee[k], r23.y, acc.w);
      }
      j = 16;
    }
    int lim8 = cnt & ~7;
    for (; j < lim8; j += 8) {
      int ss[8]; float ee[8];
#pragma unroll
      for (int k = 0; k < 8; ++k) { ss[k] = __shfl(sl, j + k, 16); ee[k] = __shfl(ev, j + k, 16); }
      uint2 rr[8];
#pragma unroll
      for (int k = 0; k < 8; ++k) rr[k] = *(const uint2*)&h2h[(size_t)ss[k] * 32 + q * 2];
#pragma unroll
      for (int k = 0; k < 8; ++k) {
        float2 r01 = __half22float2(i2h((int)rr[k].x));
        float2 r23 = __half22float2(i2h((int)rr[k].y));
        se += ee[k];
        acc.x = fmaf(ee[k], r01.x, acc.x);
        acc.y = fmaf(ee[k], r01.y, acc.y);
        acc.z = fmaf(ee[k], r23.x, acc.z);
        acc.w = fmaf(ee[k], r23.y, acc.w);
      }
    }
    for (; j < cnt; ++j) {
      int s0 = __shfl(sl, j, 16);
      float e0 = __shfl(ev, j, 16);
      uint2 rv = *(const uint2*)&h2h[(size_t)s0 * 32 + q * 2];
      float2 r01 = __half22float2(i2h((int)rv.x));
      float2 r23 = __half22float2(i2h((int)rv.y));
      se += e0;
      acc.x = fmaf(e0, r01.x, acc.x);
      acc.y = fmaf(e0, r01.y, acc.y);
      acc.z = fmaf(e0, r23.x, acc.z);
      acc.w = fmaf(e0, r23.y, acc.w);
    }
  }
  float4 o = {0, 0, 0, 0};
  if (act) {
    float inv = 1.f / se;
    o.x = fmaf(acc.x, inv, bias.x);
    o.y = fmaf(acc.y, inv, bias.y);
    o.z = fmaf(acc.z, inv, bias.z);
    o.w = fmaf(acc.w, inv, bias.w);
    unsigned p01 = (unsigned)h2i(__floats2half2_rn(o.x, o.y));
    unsigned p23 = (unsigned)h2i(__floats2half2_rn(o.z, o.w));
    *(uint2*)&v2h[(size_t)n * 32 + q * 2] = make_uint2(p01, p23);
  }
  __shared__ float4 reds[4][64], redq[4][64];
  reds[w][lane] = o;
  redq[w][lane] = make_float4(o.x * o.x, o.y * o.y, o.z * o.z, o.w * o.w);
  __syncthreads();
  if (t < 64) {
    int qq = t >> 2, ii = t & 3;
    float s = 0.f, sq = 0.f;
#pragma unroll
    for (int w2 = 0; w2 < 4; ++w2)
#pragma unroll
      for (int g2 = 0; g2 < 4; ++g2) {
        s  += (&reds[w2][g2 * 16 + qq].x)[ii];
        sq += (&redq[w2][g2 * 16 + qq].x)[ii];
      }
    int sl8 = (blockIdx.x & 7) * 128;
    atomicAdd(&stats[sl8 + t], s);
    atomicAdd(&stats[sl8 + 64 + t], sq);
  }
}

// ====== Final: out = relu(bn(v2h)) @ linW + linb, 2 nodes/wave, shared BN ======
__global__ __launch_bounds__(256) void k_out(
    const unsigned* __restrict__ v2h, const float* __restrict__ stats,
    const float* __restrict__ g2, const float* __restrict__ be2,
    const float* __restrict__ linW, const float* __restrict__ linb,
    float* __restrict__ out, int N, float rcpN)
{
  __shared__ float kc[64], sc[64], lw[64];
  int t = threadIdx.x;
  if (t < 64) {
    float su = 0.f, sq = 0.f;
#pragma unroll
    for (int s8 = 0; s8 < 8; ++s8) { su += stats[s8 * 128 + t]; sq += stats[s8 * 128 + 64 + t]; }
    float mu = su * rcpN;
    float var = sq * rcpN - mu * mu;
    float kk = g2[t] * rsqrtf(var + 1e-5f);
    kc[t] = kk; sc[t] = be2[t] - mu * kk; lw[t] = linW[t];
  }
  __syncthreads();
  int w = t >> 6, lane = t & 63, g = lane >> 5, q = lane & 31;
  int n = blockIdx.x * 8 + w * 2 + g;
  if (n >= N) return;
  unsigned uv = v2h[(size_t)n * 32 + q];
  float2 vf = __half22float2(i2h((int)uv));
  float h0 = fmaxf(vf.x * kc[2 * q] + sc[2 * q], 0.f);
  float h1 = fmaxf(vf.y * kc[2 * q + 1] + sc[2 * q + 1], 0.f);
  float p = fmaf(h0, lw[2 * q], h1 * lw[2 * q + 1]);
#pragma unroll
  for (int off = 16; off; off >>= 1) p += __shfl_xor(p, off, 32);
  if (q == 0) out[n] = p + linb[0];
}

extern "C" void kernel_launch(void* const* d_in, const int* in_sizes, int n_in,
                              void* d_out, int out_size, void* d_ws, size_t ws_size,
                              hipStream_t stream)
{
  const float* x    = (const float*)d_in[0];
  const int*   ei   = (const int*)d_in[1];
  const float* W1   = (const float*)d_in[2];
  const float* as1  = (const float*)d_in[3];
  const float* ad1  = (const float*)d_in[4];
  const float* b1   = (const float*)d_in[5];
  const float* g1   = (const float*)d_in[6];
  const float* be1  = (const float*)d_in[7];
  const float* W2   = (const float*)d_in[8];
  const float* as2  = (const float*)d_in[9];
  const float* ad2  = (const float*)d_in[10];
  const float* b2   = (const float*)d_in[11];
  const float* g2   = (const float*)d_in[12];
  const float* be2  = (const float*)d_in[13];
  const float* linW = (const float*)d_in[14];
  const float* linb = (const float*)d_in[15];
  float* out = (float*)d_out;

  int N = in_sizes[0] / 128;
  int E = in_sizes[1] / 2;
  int Etot = E + N;
  float rcpN = 1.f / (float)N;
  int PB = (N + 127) / 128;

  float* ws = (float*)d_ws;
  size_t o = 0;
  float* H1HF = ws + o; o += (size_t)N * 64;
  float* V1HF = ws + o; o += (size_t)N * 64;
  float* A1S  = ws + o; o += (size_t)N * 2;
  float* A1D  = ws + o; o += (size_t)N * 2;
  float* A2S  = ws + o; o += N;
  float* A2D  = ws + o; o += N;
  float* ST1  = ws + o; o += 8 * 256;          // zero region start
  float* ST2  = ws + o; o += 8 * 128;
  int* GBCNT  = (int*)(ws + o); o += MAXB;     // zero region end
  int* PBASE  = (int*)(ws + o); o += MAXB + 1;
  int* GCUR   = (int*)(ws + o); o += MAXB;
  int* ROWPTR = (int*)(ws + o); o += (size_t)N + 1;
  int* COL    = (int*)(ws + o); o += (size_t)Etot;
  int2* PAIRS = (int2*)(ws + o); o += (size_t)E * 2;
  unsigned* H1H = (unsigned*)H1HF;
  unsigned* H2H = (unsigned*)H1HF;
  unsigned* V1H = (unsigned*)V1HF;
  unsigned* V2H = (unsigned*)V1HF;

  hipMemsetAsync(ST1, 0, (3072 + MAXB) * 4, stream);

  int gb  = (N + 63) / 64;
  int bh  = (E + 2047) / 2048;
  int pt  = (E + 4095) / 4096;
  int ab1 = (N + 15) / 16;
  int ab2 = (N + 15) / 16;
  int ob  = (N + 7) / 8;

  k_bhist<<<bh, 256, 0, stream>>>(ei, GBCNT, E, PB);
  k_bscan<<<1, 512, 0, stream>>>(GBCNT, PBASE, GCUR, PB);
  k_part<<<pt, 256, 0, stream>>>(ei, GCUR, PAIRS, E, PB);
  k_fine<<<PB, 256, 0, stream>>>(PAIRS, PBASE, ROWPTR, COL, N);
  k_gemm1<<<gb, 256, 0, stream>>>(x, W1, as1, ad1, H1H, A1S, A1D, N);
  k_agg1<<<ab1, 256, 0, stream>>>(ROWPTR, COL, H1H, A1S, A1D, b1, V1H, ST1, N);
  k_gemm2<<<gb, 256, 0, stream>>>(V1H, W2, ST1, g1, be1, as2, ad2, H2H, A2S, A2D, N, rcpN);
  k_agg2<<<ab2, 256, 0, stream>>>(ROWPTR, COL, H2H, A2S, A2D, b2, V2H, ST2, N);
  k_out<<<ob, 256, 0, stream>>>(V2H, ST2, g2, be2, linW, linb, out, N, rcpN);
}

// Round 15
// 158.400 us; speedup vs baseline: 1.1333x; 1.0556x over previous
//
#include <hip/hip_runtime.h>
#include <hip/hip_fp16.h>
#include <math.h>

#define LEAKY 0.2f
#define XPAD 136   // 128 + 8 halves row pad
#define MAXB 512   // max dst-buckets (128 nodes each; N<=65536)

typedef _Float16 f16x8 __attribute__((ext_vector_type(8)));
typedef float f32x4 __attribute__((ext_vector_type(4)));

__device__ inline int h2i(__half2 h) { union { __half2 h; int i; } u; u.h = h; return u.i; }
__device__ inline __half2 i2h(int i) { union { __half2 h; int i; } u; u.i = i; return u.h; }

// ====== CSR build: bucketed partition ======
__global__ __launch_bounds__(256) void k_bhist(const int* __restrict__ ei,
                                               int* __restrict__ gbcnt, int E, int PB)
{
  __shared__ int lh[MAXB];
  int t = threadIdx.x;
  for (int i = t; i < PB; i += 256) lh[i] = 0;
  __syncthreads();
  int base = blockIdx.x * 2048;
#pragma unroll
  for (int k = 0; k < 8; ++k) {
    int idx = base + t + k * 256;
    if (idx < E) atomicAdd(&lh[ei[E + idx] >> 7], 1);
  }
  __syncthreads();
  for (int i = t; i < PB; i += 256) if (lh[i]) atomicAdd(&gbcnt[i], lh[i]);
}

// partition: in-block pbase scan of gbcnt; relative global cursors; contiguous runs
__global__ __launch_bounds__(256) void k_part(const int* __restrict__ ei,
                                              const int* __restrict__ gbcnt,
                                              int* __restrict__ gcur,
                                              int2* __restrict__ pairs, int E, int PB)
{
  __shared__ int lcnt[MAXB], lpb[MAXB], lbase[MAXB], ls[256];
  int t = threadIdx.x;
  for (int i = t; i < PB; i += 256) lcnt[i] = 0;
  int ea = (2 * t < PB) ? gbcnt[2 * t] : 0;
  int eb = (2 * t + 1 < PB) ? gbcnt[2 * t + 1] : 0;
  int s = ea + eb;
  ls[t] = s;
  __syncthreads();
  int base = blockIdx.x * 4096;
  int lsrc[16], ldst[16], lp[16];
#pragma unroll
  for (int k = 0; k < 16; ++k) {
    int idx = base + t + k * 256;
    lp[k] = -1;
    if (idx < E) {
      int sv = ei[idx], dv = ei[E + idx];
      lsrc[k] = sv; ldst[k] = dv;
      int b = dv >> 7;
      int p = atomicAdd(&lcnt[b], 1);
      lp[k] = (p << 10) | b;
    }
  }
  // scan ls (256) -> exclusive bucket-pair bases
  for (int off = 1; off < 256; off <<= 1) {
    int u = (t >= off) ? ls[t - off] : 0;
    __syncthreads();
    ls[t] += u;
    __syncthreads();
  }
  int excl = ls[t] - s;
  if (2 * t < MAXB) lpb[2 * t] = excl;
  if (2 * t + 1 < MAXB) lpb[2 * t + 1] = excl + ea;
  __syncthreads();
  for (int b = t; b < PB; b += 256) lbase[b] = lpb[b] + atomicAdd(&gcur[b], lcnt[b]);
  __syncthreads();
#pragma unroll
  for (int k = 0; k < 16; ++k) {
    if (lp[k] >= 0) {
      int b = lp[k] & 1023, p = lp[k] >> 10;
      pairs[lbase[b] + p] = make_int2(lsrc[k], ldst[k]);
    }
  }
}

// per-bucket: in-block e0 reduce; local deg (+1 self) -> scan = rowptr -> LDS scatter
__global__ __launch_bounds__(256) void k_fine(const int2* __restrict__ pairs,
                                              const int* __restrict__ gbcnt,
                                              int* __restrict__ rowptr,
                                              int* __restrict__ colx, int N)
{
  __shared__ int ldeg[128], lcur[128], lred[256];
  int b = blockIdx.x, t = threadIdx.x;
  int nbase = b << 7;
  int nbn = N - nbase; if (nbn > 128) nbn = 128;
  int part = 0;
  for (int i = t; i < b; i += 256) part += gbcnt[i];
  lred[t] = part;
  if (t < 128) ldeg[t] = (t < nbn) ? 1 : 0;
  __syncthreads();
  for (int off = 128; off; off >>= 1) {
    if (t < off) lred[t] += lred[t + off];
    __syncthreads();
  }
  int e0 = lred[0];
  int e1 = e0 + gbcnt[b];
  for (int e = e0 + t; e < e1; e += 256) atomicAdd(&ldeg[pairs[e].y - nbase], 1);
  __syncthreads();
  int myv = (t < 128) ? ldeg[t] : 0;
  for (int off = 1; off < 128; off <<= 1) {
    int u = (t < 128 && t >= off) ? ldeg[t - off] : 0;
    __syncthreads();
    if (t < 128) ldeg[t] += u;
    __syncthreads();
  }
  int colx0 = e0 + nbase;
  if (t < 128) {
    int excl = ldeg[t] - myv;
    lcur[t] = colx0 + excl;
    int idx = nbase + t;
    if (idx <= N) rowptr[idx] = colx0 + excl;
  }
  __syncthreads();
  for (int e = e0 + t; e < e1; e += 256) {
    int2 p = pairs[e];
    int pos = atomicAdd(&lcur[p.y - nbase], 1);
    colx[pos] = p.x;
  }
  if (t < nbn) {
    int pos = atomicAdd(&lcur[t], 1);
    colx[pos] = nbase + t;
  }
}

// ====== GEMM1 (MFMA): h1 = x @ W1, fp16 out, fused att dots ======
__global__ __launch_bounds__(256) void k_gemm1(
    const float* __restrict__ x, const float* __restrict__ W,
    const float* __restrict__ att_s, const float* __restrict__ att_d,
    unsigned* __restrict__ h1h, float* __restrict__ a1s, float* __restrict__ a1d, int N)
{
  __shared__ __align__(16) _Float16 Xh[64 * XPAD];
  __shared__ __align__(16) _Float16 Wt[128 * XPAD];
  int t = threadIdx.x;
  const float4* W4 = (const float4*)W;
#pragma unroll
  for (int i = 0; i < 16; ++i) {
    int id = t + i * 256;
    int row = id >> 5, c0 = (id & 31) * 4;
    float4 wv = W4[id];
    Wt[(c0    ) * XPAD + row] = (_Float16)wv.x;
    Wt[(c0 + 1) * XPAD + row] = (_Float16)wv.y;
    Wt[(c0 + 2) * XPAD + row] = (_Float16)wv.z;
    Wt[(c0 + 3) * XPAD + row] = (_Float16)wv.w;
  }
  int row0 = blockIdx.x * 64;
  const float4* X4 = (const float4*)x;
#pragma unroll
  for (int i = 0; i < 8; ++i) {
    int id = t + i * 256;
    int r = id >> 5, c = id & 31;
    int gr = row0 + r;
    float4 v = (gr < N) ? X4[(size_t)gr * 32 + c] : make_float4(0.f, 0.f, 0.f, 0.f);
    unsigned p01 = (unsigned)h2i(__floats2half2_rn(v.x, v.y));
    unsigned p23 = (unsigned)h2i(__floats2half2_rn(v.z, v.w));
    *(uint2*)&Xh[r * XPAD + c * 4] = make_uint2(p01, p23);
  }
  __syncthreads();
  int w = t >> 6, l = t & 63;
  int m = l & 15, kg = l >> 4;
  f32x4 acc[8];
#pragma unroll
  for (int c = 0; c < 8; ++c) { acc[c][0] = 0.f; acc[c][1] = 0.f; acc[c][2] = 0.f; acc[c][3] = 0.f; }
#pragma unroll
  for (int ks = 0; ks < 4; ++ks) {
    f16x8 a = *(const f16x8*)&Xh[(w * 16 + m) * XPAD + ks * 32 + kg * 8];
#pragma unroll
    for (int c = 0; c < 8; ++c) {
      f16x8 bfr = *(const f16x8*)&Wt[(c * 16 + m) * XPAD + ks * 32 + kg * 8];
      acc[c] = __builtin_amdgcn_mfma_f32_16x16x32_f16(a, bfr, acc[c], 0, 0, 0);
    }
  }
#pragma unroll
  for (int c = 0; c < 8; ++c)
#pragma unroll
    for (int r = 0; r < 4; ++r)
      Xh[(w * 16 + kg * 4 + r) * XPAD + c * 16 + m] = (_Float16)acc[c][r];
  __syncthreads();
#pragma unroll
  for (int i = 0; i < 8; ++i) {
    int id = t + i * 256;
    int r = id >> 5, c4 = id & 31;
    int gr = row0 + r;
    uint2 pk = *(const uint2*)&Xh[r * XPAD + c4 * 4];
    float2 v01 = __half22float2(i2h((int)pk.x));
    float2 v23 = __half22float2(i2h((int)pk.y));
    int col = c4 * 4;
    float4 asv = *(const float4*)&att_s[col];
    float4 adv = *(const float4*)&att_d[col];
    float ps = v01.x * asv.x + v01.y * asv.y + v23.x * asv.z + v23.y * asv.w;
    float pd = v01.x * adv.x + v01.y * adv.y + v23.x * adv.z + v23.y * adv.w;
    ps += __shfl_xor(ps, 1); ps += __shfl_xor(ps, 2); ps += __shfl_xor(ps, 4); ps += __shfl_xor(ps, 8);
    pd += __shfl_xor(pd, 1); pd += __shfl_xor(pd, 2); pd += __shfl_xor(pd, 4); pd += __shfl_xor(pd, 8);
    if (gr < N) {
      *(uint2*)&h1h[(size_t)gr * 64 + c4 * 2] = pk;
      if ((t & 15) == 0) { int h = (t >> 4) & 1; a1s[gr * 2 + h] = ps; a1d[gr * 2 + h] = pd; }
    }
  }
}

// ====== Aggregate layer 1: FOUR nodes/wave (16-lane groups, uint4 row), fused BN stats ======
__global__ __launch_bounds__(256) void k_agg1(
    const int* __restrict__ rowptr, const int* __restrict__ colx,
    const unsigned* __restrict__ h1h, const float* __restrict__ a1s,
    const float* __restrict__ a1d, const float* __restrict__ b1,
    unsigned* __restrict__ v1h, float* __restrict__ stats, int N)
{
  int t = threadIdx.x;
  int w = t >> 6, lane = t & 63;
  int g = lane >> 4, q = lane & 15;
  bool hi = q >= 8;
  int n = blockIdx.x * 16 + w * 4 + g;
  bool act = n < N;
  float4 biasA = *(const float4*)&b1[q * 8];
  float4 biasB = *(const float4*)&b1[q * 8 + 4];
  int start = 0, end = 0;
  float2 ad = make_float2(0.f, 0.f);
  if (act) { start = rowptr[n]; end = rowptr[n + 1]; ad = *(const float2*)&a1d[n * 2]; }
  float se = 0.f;
  float4 accA = {0, 0, 0, 0}, accB = {0, 0, 0, 0};
  for (int base = start; base < end; base += 16) {
    int cnt = end - base; if (cnt > 16) cnt = 16;
    int sl = 0, epk = 0;
    if (q < cnt) {
      sl = colx[base + q];
      float2 av = *(const float2*)&a1s[sl * 2];
      float x0 = av.x + ad.x, x1 = av.y + ad.y;
      x0 = (x0 > 0.f) ? x0 : LEAKY * x0;
      x1 = (x1 > 0.f) ? x1 : LEAKY * x1;
      epk = h2i(__floats2half2_rn(__expf(x0), __expf(x1)));
    }
    int j = 0;
    if (cnt == 16) {
      int ss[16], ee[16];
#pragma unroll
      for (int k = 0; k < 16; ++k) { ss[k] = __shfl(sl, k, 16); ee[k] = __shfl(epk, k, 16); }
      uint4 rr[16];
#pragma unroll
      for (int k = 0; k < 16; ++k) rr[k] = *(const uint4*)&h1h[(size_t)ss[k] * 64 + q * 4];
#pragma unroll
      for (int k = 0; k < 16; ++k) {
        float2 ef = __half22float2(i2h(ee[k]));
        float wg = hi ? ef.y : ef.x;
        float2 r0 = __half22float2(i2h((int)rr[k].x));
        float2 r1 = __half22float2(i2h((int)rr[k].y));
        float2 r2 = __half22float2(i2h((int)rr[k].z));
        float2 r3 = __half22float2(i2h((int)rr[k].w));
        se += wg;
        accA.x = fmaf(wg, r0.x, accA.x); accA.y = fmaf(wg, r0.y, accA.y);
        accA.z = fmaf(wg, r1.x, accA.z); accA.w = fmaf(wg, r1.y, accA.w);
        accB.x = fmaf(wg, r2.x, accB.x); accB.y = fmaf(wg, r2.y, accB.y);
        accB.z = fmaf(wg, r3.x, accB.z); accB.w = fmaf(wg, r3.y, accB.w);
      }
      j = 16;
    }
    int lim8 = cnt & ~7;
    for (; j < lim8; j += 8) {
      int ss[8], ee[8];
#pragma unroll
      for (int k = 0; k < 8; ++k) { ss[k] = __shfl(sl, j + k, 16); ee[k] = __shfl(epk, j + k, 16); }
      uint4 rr[8];
#pragma unroll
      for (int k = 0; k < 8; ++k) rr[k] = *(const uint4*)&h1h[(size_t)ss[k] * 64 + q * 4];
#pragma unroll
      for (int k = 0; k < 8; ++k) {
        float2 ef = __half22float2(i2h(ee[k]));
        float wg = hi ? ef.y : ef.x;
        float2 r0 = __half22float2(i2h((int)rr[k].x));
        float2 r1 = __half22float2(i2h((int)rr[k].y));
        float2 r2 = __half22float2(i2h((int)rr[k].z));
        float2 r3 = __half22float2(i2h((int)rr[k].w));
        se += wg;
        accA.x = fmaf(wg, r0.x, accA.x); accA.y = fmaf(wg, r0.y, accA.y);
        accA.z = fmaf(wg, r1.x, accA.z); accA.w = fmaf(wg, r1.y, accA.w);
        accB.x = fmaf(wg, r2.x, accB.x); accB.y = fmaf(wg, r2.y, accB.y);
        accB.z = fmaf(wg, r3.x, accB.z); accB.w = fmaf(wg, r3.y, accB.w);
      }
    }
    for (; j < cnt; ++j) {
      int s0 = __shfl(sl, j, 16), e0 = __shfl(epk, j, 16);
      float2 ef = __half22float2(i2h(e0));
      float wg = hi ? ef.y : ef.x;
      uint4 rv = *(const uint4*)&h1h[(size_t)s0 * 64 + q * 4];
      float2 r0 = __half22float2(i2h((int)rv.x));
      float2 r1 = __half22float2(i2h((int)rv.y));
      float2 r2 = __half22float2(i2h((int)rv.z));
      float2 r3 = __half22float2(i2h((int)rv.w));
      se += wg;
      accA.x = fmaf(wg, r0.x, accA.x); accA.y = fmaf(wg, r0.y, accA.y);
      accA.z = fmaf(wg, r1.x, accA.z); accA.w = fmaf(wg, r1.y, accA.w);
      accB.x = fmaf(wg, r2.x, accB.x); accB.y = fmaf(wg, r2.y, accB.y);
      accB.z = fmaf(wg, r3.x, accB.z); accB.w = fmaf(wg, r3.y, accB.w);
    }
  }
  float4 oA = {0,0,0,0}, oB = {0,0,0,0};
  if (act) {
    float inv = 1.f / se;
    oA.x = fmaf(accA.x, inv, biasA.x);
    oA.y = fmaf(accA.y, inv, biasA.y);
    oA.z = fmaf(accA.z, inv, biasA.z);
    oA.w = fmaf(accA.w, inv, biasA.w);
    oB.x = fmaf(accB.x, inv, biasB.x);
    oB.y = fmaf(accB.y, inv, biasB.y);
    oB.z = fmaf(accB.z, inv, biasB.z);
    oB.w = fmaf(accB.w, inv, biasB.w);
    unsigned p0 = (unsigned)h2i(__floats2half2_rn(oA.x, oA.y));
    unsigned p1 = (unsigned)h2i(__floats2half2_rn(oA.z, oA.w));
    unsigned p2 = (unsigned)h2i(__floats2half2_rn(oB.x, oB.y));
    unsigned p3 = (unsigned)h2i(__floats2half2_rn(oB.z, oB.w));
    *(uint4*)&v1h[(size_t)n * 64 + q * 4] = make_uint4(p0, p1, p2, p3);
  }
  __shared__ float redS[4][64][9], redQ[4][64][9];   // [9] pad: stride 9 coprime 32 banks
#pragma unroll
  for (int j2 = 0; j2 < 4; ++j2) {
    redS[w][lane][j2]     = (&oA.x)[j2];
    redS[w][lane][4 + j2] = (&oB.x)[j2];
    redQ[w][lane][j2]     = (&oA.x)[j2] * (&oA.x)[j2];
    redQ[w][lane][4 + j2] = (&oB.x)[j2] * (&oB.x)[j2];
  }
  __syncthreads();
  if (t < 128) {
    int qq = t >> 3, jj = t & 7;
    float s = 0.f, sq = 0.f;
#pragma unroll
    for (int w2 = 0; w2 < 4; ++w2)
#pragma unroll
      for (int g2 = 0; g2 < 4; ++g2) {
        s  += redS[w2][g2 * 16 + qq][jj];
        sq += redQ[w2][g2 * 16 + qq][jj];
      }
    int sl8 = (blockIdx.x & 7) * 256;
    atomicAdd(&stats[sl8 + t], s);
    atomicAdd(&stats[sl8 + 128 + t], sq);
  }
}

// ====== GEMM2 (MFMA): h2 = relu(bn(v1h)) @ W2, fp16 out ======
__global__ __launch_bounds__(256) void k_gemm2(
    const unsigned* __restrict__ v1h, const float* __restrict__ W2,
    const float* __restrict__ stats, const float* __restrict__ g1, const float* __restrict__ be1,
    const float* __restrict__ att_s, const float* __restrict__ att_d,
    unsigned* __restrict__ h2h, float* __restrict__ a2s, float* __restrict__ a2d,
    int N, float rcpN)
{
  __shared__ __align__(16) _Float16 Xh[64 * XPAD];
  __shared__ __align__(16) _Float16 Wt[64 * XPAD];
  __shared__ float kc[128], sc[128];
  int t = threadIdx.x;
  if (t < 128) {
    float su = 0.f, sq = 0.f;
#pragma unroll
    for (int s8 = 0; s8 < 8; ++s8) { su += stats[s8 * 256 + t]; sq += stats[s8 * 256 + 128 + t]; }
    float mu = su * rcpN;
    float var = sq * rcpN - mu * mu;
    float kk = g1[t] * rsqrtf(var + 1e-5f);
    kc[t] = kk; sc[t] = be1[t] - mu * kk;
  }
  const float4* W4 = (const float4*)W2;
#pragma unroll
  for (int i = 0; i < 8; ++i) {
    int id = t + i * 256;
    int row = id >> 4, c0 = (id & 15) * 4;
    float4 wv = W4[id];
    Wt[(c0    ) * XPAD + row] = (_Float16)wv.x;
    Wt[(c0 + 1) * XPAD + row] = (_Float16)wv.y;
    Wt[(c0 + 2) * XPAD + row] = (_Float16)wv.z;
    Wt[(c0 + 3) * XPAD + row] = (_Float16)wv.w;
  }
  __syncthreads();
  int row0 = blockIdx.x * 64;
#pragma unroll
  for (int i = 0; i < 8; ++i) {
    int id = t + i * 256;
    int r = id >> 5, c4 = id & 31;
    int gr = row0 + r;
    uint2 pv = (gr < N) ? *(const uint2*)&v1h[(size_t)gr * 64 + c4 * 2] : make_uint2(0, 0);
    float2 a01 = __half22float2(i2h((int)pv.x));
    float2 a23 = __half22float2(i2h((int)pv.y));
    int f0 = c4 * 4;
    float o0 = fmaxf(a01.x * kc[f0]     + sc[f0],     0.f);
    float o1 = fmaxf(a01.y * kc[f0 + 1] + sc[f0 + 1], 0.f);
    float o2 = fmaxf(a23.x * kc[f0 + 2] + sc[f0 + 2], 0.f);
    float o3 = fmaxf(a23.y * kc[f0 + 3] + sc[f0 + 3], 0.f);
    unsigned p01 = (unsigned)h2i(__floats2half2_rn(o0, o1));
    unsigned p23 = (unsigned)h2i(__floats2half2_rn(o2, o3));
    *(uint2*)&Xh[r * XPAD + c4 * 4] = make_uint2(p01, p23);
  }
  __syncthreads();
  int w = t >> 6, l = t & 63;
  int m = l & 15, kg = l >> 4;
  f32x4 acc[4];
#pragma unroll
  for (int c = 0; c < 4; ++c) { acc[c][0] = 0.f; acc[c][1] = 0.f; acc[c][2] = 0.f; acc[c][3] = 0.f; }
#pragma unroll
  for (int ks = 0; ks < 4; ++ks) {
    f16x8 a = *(const f16x8*)&Xh[(w * 16 + m) * XPAD + ks * 32 + kg * 8];
#pragma unroll
    for (int c = 0; c < 4; ++c) {
      f16x8 bfr = *(const f16x8*)&Wt[(c * 16 + m) * XPAD + ks * 32 + kg * 8];
      acc[c] = __builtin_amdgcn_mfma_f32_16x16x32_f16(a, bfr, acc[c], 0, 0, 0);
    }
  }
#pragma unroll
  for (int c = 0; c < 4; ++c)
#pragma unroll
    for (int r = 0; r < 4; ++r)
      Xh[(w * 16 + kg * 4 + r) * XPAD + c * 16 + m] = (_Float16)acc[c][r];
  __syncthreads();
#pragma unroll
  for (int i = 0; i < 4; ++i) {
    int id = t + i * 256;
    int r = id >> 4, c4 = id & 15;
    int gr = row0 + r;
    uint2 pk = *(const uint2*)&Xh[r * XPAD + c4 * 4];
    float2 v01 = __half22float2(i2h((int)pk.x));
    float2 v23 = __half22float2(i2h((int)pk.y));
    int col = c4 * 4;
    float4 asv = *(const float4*)&att_s[col];
    float4 adv = *(const float4*)&att_d[col];
    float ps = v01.x * asv.x + v01.y * asv.y + v23.x * asv.z + v23.y * asv.w;
    float pd = v01.x * adv.x + v01.y * adv.y + v23.x * adv.z + v23.y * adv.w;
    ps += __shfl_xor(ps, 1); ps += __shfl_xor(ps, 2); ps += __shfl_xor(ps, 4); ps += __shfl_xor(ps, 8);
    pd += __shfl_xor(pd, 1); pd += __shfl_xor(pd, 2); pd += __shfl_xor(pd, 4); pd += __shfl_xor(pd, 8);
    if (gr < N) {
      *(uint2*)&h2h[(size_t)gr * 32 + c4 * 2] = pk;
      if ((t & 15) == 0) { a2s[gr] = ps; a2d[gr] = pd; }
    }
  }
}

// ====== Aggregate layer 2: EIGHT nodes/wave (8-lane groups, uint4 = full 128B row) ======
__global__ __launch_bounds__(256) void k_agg2(
    const int* __restrict__ rowptr, const int* __restrict__ colx,
    const unsigned* __restrict__ h2h, const float* __restrict__ a2s,
    const float* __restrict__ a2d, const float* __restrict__ b2,
    unsigned* __restrict__ v2h, float* __restrict__ stats, int N)
{
  int t = threadIdx.x;
  int w = t >> 6, lane = t & 63;
  int g = lane >> 3, q = lane & 7;      // 8 node-groups x 8 lanes
  int n = blockIdx.x * 32 + w * 8 + g;
  bool act = n < N;
  float4 biasA = *(const float4*)&b2[q * 8];
  float4 biasB = *(const float4*)&b2[q * 8 + 4];
  int start = 0, end = 0;
  float ad = 0.f;
  if (act) { start = rowptr[n]; end = rowptr[n + 1]; ad = a2d[n]; }
  float se = 0.f;
  float4 accA = {0, 0, 0, 0}, accB = {0, 0, 0, 0};
  for (int base = start; base < end; base += 8) {
    int cnt = end - base; if (cnt > 8) cnt = 8;
    int sl = 0; float ev = 0.f;
    if (q < cnt) {
      sl = colx[base + q];
      float av = a2s[sl] + ad;
      av = (av > 0.f) ? av : LEAKY * av;
      ev = __expf(av);
    }
    int j = 0;
    if (cnt == 8) {
      int ss[8]; float ee[8];
#pragma unroll
      for (int k = 0; k < 8; ++k) { ss[k] = __shfl(sl, k, 8); ee[k] = __shfl(ev, k, 8); }
      uint4 rr[8];
#pragma unroll
      for (int k = 0; k < 8; ++k) rr[k] = *(const uint4*)&h2h[(size_t)ss[k] * 32 + q * 4];
#pragma unroll
      for (int k = 0; k < 8; ++k) {
        float2 r0 = __half22float2(i2h((int)rr[k].x));
        float2 r1 = __half22float2(i2h((int)rr[k].y));
        float2 r2 = __half22float2(i2h((int)rr[k].z));
        float2 r3 = __half22float2(i2h((int)rr[k].w));
        se += ee[k];
        accA.x = fmaf(ee[k], r0.x, accA.x); accA.y = fmaf(ee[k], r0.y, accA.y);
        accA.z = fmaf(ee[k], r1.x, accA.z); accA.w = fmaf(ee[k], r1.y, accA.w);
        accB.x = fmaf(ee[k], r2.x, accB.x); accB.y = fmaf(ee[k], r2.y, accB.y);
        accB.z = fmaf(ee[k], r3.x, accB.z); accB.w = fmaf(ee[k], r3.y, accB.w);
      }
      j = 8;
    }
    int lim4 = cnt & ~3;
    for (; j < lim4; j += 4) {
      int ss[4]; float ee[4];
#pragma unroll
      for (int k = 0; k < 4; ++k) { ss[k] = __shfl(sl, j + k, 8); ee[k] = __shfl(ev, j + k, 8); }
      uint4 rr[4];
#pragma unroll
      for (int k = 0; k < 4; ++k) rr[k] = *(const uint4*)&h2h[(size_t)ss[k] * 32 + q * 4];
#pragma unroll
      for (int k = 0; k < 4; ++k) {
        float2 r0 = __half22float2(i2h((int)rr[k].x));
        float2 r1 = __half22float2(i2h((int)rr[k].y));
        float2 r2 = __half22float2(i2h((int)rr[k].z));
        float2 r3 = __half22float2(i2h((int)rr[k].w));
        se += ee[k];
        accA.x = fmaf(ee[k], r0.x, accA.x); accA.y = fmaf(ee[k], r0.y, accA.y);
        accA.z = fmaf(ee[k], r1.x, accA.z); accA.w = fmaf(ee[k], r1.y, accA.w);
        accB.x = fmaf(ee[k], r2.x, accB.x); accB.y = fmaf(ee[k], r2.y, accB.y);
        accB.z = fmaf(ee[k], r3.x, accB.z); accB.w = fmaf(ee[k], r3.y, accB.w);
      }
    }
    for (; j < cnt; ++j) {
      int s0 = __shfl(sl, j, 8);
      float e0 = __shfl(ev, j, 8);
      uint4 rv = *(const uint4*)&h2h[(size_t)s0 * 32 + q * 4];
      float2 r0 = __half22float2(i2h((int)rv.x));
      float2 r1 = __half22float2(i2h((int)rv.y));
      float2 r2 = __half22float2(i2h((int)rv.z));
      float2 r3 = __half22float2(i2h((int)rv.w));
      se += e0;
      accA.x = fmaf(e0, r0.x, accA.x); accA.y = fmaf(e0, r0.y, accA.y);
      accA.z = fmaf(e0, r1.x, accA.z); accA.w = fmaf(e0, r1.y, accA.w);
      accB.x = fmaf(e0, r2.x, accB.x); accB.y = fmaf(e0, r2.y, accB.y);
      accB.z = fmaf(e0, r3.x, accB.z); accB.w = fmaf(e0, r3.y, accB.w);
    }
  }
  float4 oA = {0,0,0,0}, oB = {0,0,0,0};
  if (act) {
    float inv = 1.f / se;
    oA.x = fmaf(accA.x, inv, biasA.x);
    oA.y = fmaf(accA.y, inv, biasA.y);
    oA.z = fmaf(accA.z, inv, biasA.z);
    oA.w = fmaf(accA.w, inv, biasA.w);
    oB.x = fmaf(accB.x, inv, biasB.x);
    oB.y = fmaf(accB.y, inv, biasB.y);
    oB.z = fmaf(accB.z, inv, biasB.z);
    oB.w = fmaf(accB.w, inv, biasB.w);
    unsigned p0 = (unsigned)h2i(__floats2half2_rn(oA.x, oA.y));
    unsigned p1 = (unsigned)h2i(__floats2half2_rn(oA.z, oA.w));
    unsigned p2 = (unsigned)h2i(__floats2half2_rn(oB.x, oB.y));
    unsigned p3 = (unsigned)h2i(__floats2half2_rn(oB.z, oB.w));
    *(uint4*)&v2h[(size_t)n * 32 + q * 4] = make_uint4(p0, p1, p2, p3);
  }
  __shared__ float redS[4][64][9], redQ[4][64][9];
#pragma unroll
  for (int j2 = 0; j2 < 4; ++j2) {
    redS[w][lane][j2]     = (&oA.x)[j2];
    redS[w][lane][4 + j2] = (&oB.x)[j2];
    redQ[w][lane][j2]     = (&oA.x)[j2] * (&oA.x)[j2];
    redQ[w][lane][4 + j2] = (&oB.x)[j2] * (&oB.x)[j2];
  }
  __syncthreads();
  if (t < 64) {
    int qq = t >> 3, jj = t & 7;       // feature f = 8*qq + jj = t
    float s = 0.f, sq = 0.f;
#pragma unroll
    for (int w2 = 0; w2 < 4; ++w2)
#pragma unroll
      for (int g2 = 0; g2 < 8; ++g2) {
        s  += redS[w2][g2 * 8 + qq][jj];
        sq += redQ[w2][g2 * 8 + qq][jj];
      }
    int sl8 = (blockIdx.x & 7) * 128;
    atomicAdd(&stats[sl8 + t], s);
    atomicAdd(&stats[sl8 + 64 + t], sq);
  }
}

// ====== Final: out = relu(bn(v2h)) @ linW + linb, 2 nodes/wave, shared BN ======
__global__ __launch_bounds__(256) void k_out(
    const unsigned* __restrict__ v2h, const float* __restrict__ stats,
    const float* __restrict__ g2, const float* __restrict__ be2,
    const float* __restrict__ linW, const float* __restrict__ linb,
    float* __restrict__ out, int N, float rcpN)
{
  __shared__ float kc[64], sc[64], lw[64];
  int t = threadIdx.x;
  if (t < 64) {
    float su = 0.f, sq = 0.f;
#pragma unroll
    for (int s8 = 0; s8 < 8; ++s8) { su += stats[s8 * 128 + t]; sq += stats[s8 * 128 + 64 + t]; }
    float mu = su * rcpN;
    float var = sq * rcpN - mu * mu;
    float kk = g2[t] * rsqrtf(var + 1e-5f);
    kc[t] = kk; sc[t] = be2[t] - mu * kk; lw[t] = linW[t];
  }
  __syncthreads();
  int w = t >> 6, lane = t & 63, g = lane >> 5, q = lane & 31;
  int n = blockIdx.x * 8 + w * 2 + g;
  if (n >= N) return;
  unsigned uv = v2h[(size_t)n * 32 + q];
  float2 vf = __half22float2(i2h((int)uv));
  float h0 = fmaxf(vf.x * kc[2 * q] + sc[2 * q], 0.f);
  float h1 = fmaxf(vf.y * kc[2 * q + 1] + sc[2 * q + 1], 0.f);
  float p = fmaf(h0, lw[2 * q], h1 * lw[2 * q + 1]);
#pragma unroll
  for (int off = 16; off; off >>= 1) p += __shfl_xor(p, off, 32);
  if (q == 0) out[n] = p + linb[0];
}

extern "C" void kernel_launch(void* const* d_in, const int* in_sizes, int n_in,
                              void* d_out, int out_size, void* d_ws, size_t ws_size,
                              hipStream_t stream)
{
  const float* x    = (const float*)d_in[0];
  const int*   ei   = (const int*)d_in[1];
  const float* W1   = (const float*)d_in[2];
  const float* as1  = (const float*)d_in[3];
  const float* ad1  = (const float*)d_in[4];
  const float* b1   = (const float*)d_in[5];
  const float* g1   = (const float*)d_in[6];
  const float* be1  = (const float*)d_in[7];
  const float* W2   = (const float*)d_in[8];
  const float* as2  = (const float*)d_in[9];
  const float* ad2  = (const float*)d_in[10];
  const float* b2   = (const float*)d_in[11];
  const float* g2   = (const float*)d_in[12];
  const float* be2  = (const float*)d_in[13];
  const float* linW = (const float*)d_in[14];
  const float* linb = (const float*)d_in[15];
  float* out = (float*)d_out;

  int N = in_sizes[0] / 128;
  int E = in_sizes[1] / 2;
  int Etot = E + N;
  float rcpN = 1.f / (float)N;
  int PB = (N + 127) / 128;

  float* ws = (float*)d_ws;
  size_t o = 0;
  float* H1HF = ws + o; o += (size_t)N * 64;
  float* V1HF = ws + o; o += (size_t)N * 64;
  float* A1S  = ws + o; o += (size_t)N * 2;
  float* A1D  = ws + o; o += (size_t)N * 2;
  float* A2S  = ws + o; o += N;
  float* A2D  = ws + o; o += N;
  float* ST1  = ws + o; o += 8 * 256;          // zero region start
  float* ST2  = ws + o; o += 8 * 128;
  int* GBCNT  = (int*)(ws + o); o += MAXB;
  int* GCUR   = (int*)(ws + o); o += MAXB;     // zero region end (relative cursors)
  int* ROWPTR = (int*)(ws + o); o += (size_t)N + 1;
  int* COL    = (int*)(ws + o); o += (size_t)Etot;
  int2* PAIRS = (int2*)(ws + o); o += (size_t)E * 2;
  unsigned* H1H = (unsigned*)H1HF;
  unsigned* H2H = (unsigned*)H1HF;
  unsigned* V1H = (unsigned*)V1HF;
  unsigned* V2H = (unsigned*)V1HF;

  hipMemsetAsync(ST1, 0, (3072 + 2 * MAXB) * 4, stream);

  int gb  = (N + 63) / 64;
  int bh  = (E + 2047) / 2048;
  int pt  = (E + 4095) / 4096;
  int ab1 = (N + 15) / 16;
  int ab2 = (N + 31) / 32;
  int ob  = (N + 7) / 8;

  k_bhist<<<bh, 256, 0, stream>>>(ei, GBCNT, E, PB);
  k_part<<<pt, 256, 0, stream>>>(ei, GBCNT, GCUR, PAIRS, E, PB);
  k_fine<<<PB, 256, 0, stream>>>(PAIRS, GBCNT, ROWPTR, COL, N);
  k_gemm1<<<gb, 256, 0, stream>>>(x, W1, as1, ad1, H1H, A1S, A1D, N);
  k_agg1<<<ab1, 256, 0, stream>>>(ROWPTR, COL, H1H, A1S, A1D, b1, V1H, ST1, N);
  k_gemm2<<<gb, 256, 0, stream>>>(V1H, W2, ST1, g1, be1, as2, ad2, H2H, A2S, A2D, N, rcpN);
  k_agg2<<<ab2, 256, 0, stream>>>(ROWPTR, COL, H2H, A2S, A2D, b2, V2H, ST2, N);
  k_out<<<ob, 256, 0, stream>>>(V2H, ST2, g2, be2, linW, linb, out, N, rcpN);
}